// Round 3
// 29266.705 us; speedup vs baseline: 1.2080x; 1.2080x over previous
//
#include <hip/hip_runtime.h>

#define LSEQ 700
#define NB   32
#define DIN  41
#define HID  800
#define G4   3200   // 4*H gate rows
#define H2   1600   // 2*H
#define DKP  64     // Din padded to MFMA K granularity
#define NREP 4      // h-ring replicas (LLC line hotspot mitigation); replica = wave id
#define WP   808    // LDS weight row stride (f16): 808*2B=1616B -> 2-way bank alias (free)

#define SCAL 2048.f
#define ISC  (1.f/2048.f)

// full-grid gbar region: 256 arrive flags (64B stride) + 64 go words (64B stride)
#define GOOFF (256*16)
#define BARN  (256*16 + 64*16)
// per-direction barrier region: 128 arrive + 64 go, ints
#define GO_D  (128*16)
#define RST   (192*16)

typedef _Float16 h8v __attribute__((ext_vector_type(8)));  // 8 f16 = 4 VGPRs (MFMA A/B frag)
typedef float    f4v __attribute__((ext_vector_type(4)));

struct P {
  const float *x, *w_ih0, *w_hh0, *b_ih0, *b_hh0;
  const float *w_ih1, *w_hh1, *b_ih1, *b_hh1;
  const float *w_lin, *b_lin, *alphabet;
  _Float16 *h0;                    // [t][b][dir*800+u] f16 hi — full history (layer1 GEMM input)
  _Float16 *hr0h, *hr0l;           // layer0 depth-2 ring x NREP replicas [slot][rep][b][dir*800+u]
  _Float16 *r1h,  *r1l;            // layer1 depth-2 ring x NREP replicas
  _Float16 *h1wh, *h1wl;           // layer1 SL ring [slot][b][dir*800+u] (logits reads after gbar)
  _Float16 *w0hh, *w1hh;           // [dir][permrow 4u+g][800]
  _Float16 *w1ih;                  // [dir][permrow][1600]
  _Float16 *w0ih;                  // [dir][permrow][64]
  _Float16 *xp;                    // [t][b][64]
  float *bias0, *bias1;            // [dir][permrow]
  float *logits0, *logits1;        // [t][b][20]
  float *dvec;                     // [3L][j][4]
  float *gx1;                      // [d][sl][unit][b][4] f32
  float *out;
  int *bar0;                       // layer0 per-dir barrier regions [2][RST]
  int *barG;                       // layer1 full-grid gbar (phase boundaries)
  int *barS;                       // layer1 per-dir step barrier regions [2][RST]
  int Tc, nchunks;
};

__device__ __forceinline__ h8v ldv(const _Float16* p_){ return *(const h8v*)p_; }

// Full-grid fenced barrier (VERBATIM R0 semantics) — layer1 phase boundaries.
__device__ __forceinline__ void gbar(int* bar, int ep){
  __syncthreads();
  if (threadIdx.x == 0){
    __builtin_amdgcn_fence(__ATOMIC_RELEASE, "agent");   // L2 writeback to coherence point
    __hip_atomic_store(&bar[blockIdx.x*16], ep, __ATOMIC_RELAXED, __HIP_MEMORY_SCOPE_AGENT);
  }
  if (blockIdx.x == 0){
    for (int i = threadIdx.x; i < (int)gridDim.x; i += blockDim.x)
      while (__hip_atomic_load(&bar[i*16], __ATOMIC_RELAXED, __HIP_MEMORY_SCOPE_AGENT) < ep)
        __builtin_amdgcn_s_sleep(1);
    __syncthreads();
    if (threadIdx.x < 64)
      __hip_atomic_store(&bar[GOOFF + threadIdx.x*16], ep, __ATOMIC_RELAXED, __HIP_MEMORY_SCOPE_AGENT);
  } else {
    if (threadIdx.x == 0){
      while (__hip_atomic_load(&bar[GOOFF + (blockIdx.x & 63)*16], __ATOMIC_RELAXED, __HIP_MEMORY_SCOPE_AGENT) < ep)
        __builtin_amdgcn_s_sleep(1);
    }
  }
  __syncthreads();
  __builtin_amdgcn_fence(__ATOMIC_ACQUIRE, "agent");     // invalidate caches: fresh loads
}

// Per-direction fenced barrier: same release/acquire fences, same hub-and-spoke
// algorithm, scoped to the n WGs of one direction (participants pass their wgd).
// All per-step exchanged data is direction-local (verified: dir0/dir1 never share
// a 64B line in h0 or the rings), so dir-scoped gather is a full happens-before.
__device__ __forceinline__ void gbar_d(int* bar, int ep, int wgd, int n){
  __syncthreads();
  if (threadIdx.x == 0){
    __builtin_amdgcn_fence(__ATOMIC_RELEASE, "agent");
    __hip_atomic_store(&bar[wgd*16], ep, __ATOMIC_RELAXED, __HIP_MEMORY_SCOPE_AGENT);
  }
  if (wgd == 0){
    for (int i = threadIdx.x; i < n; i += blockDim.x)
      while (__hip_atomic_load(&bar[i*16], __ATOMIC_RELAXED, __HIP_MEMORY_SCOPE_AGENT) < ep)
        __builtin_amdgcn_s_sleep(1);
    __syncthreads();
    if (threadIdx.x < 64)
      __hip_atomic_store(&bar[GO_D + threadIdx.x*16], ep, __ATOMIC_RELAXED, __HIP_MEMORY_SCOPE_AGENT);
  } else {
    if (threadIdx.x == 0){
      while (__hip_atomic_load(&bar[GO_D + (wgd & 63)*16], __ATOMIC_RELAXED, __HIP_MEMORY_SCOPE_AGENT) < ep)
        __builtin_amdgcn_s_sleep(1);
    }
  }
  __syncthreads();
  __builtin_amdgcn_fence(__ATOMIC_ACQUIRE, "agent");
}

// ---- prep: permuted-row f16 weights. newrow = 4*u + gate (gate order i,f,g,o)
__global__ void prep_w(const float* __restrict__ src, _Float16* __restrict__ dst,
                       int Ks, int Kd){
  const long n = (long)2*G4*Kd;
  for (long i = blockIdx.x*(long)blockDim.x + threadIdx.x; i < n; i += (long)gridDim.x*blockDim.x){
    const int k  = (int)(i % Kd);
    const long rr = i / Kd;
    const int nr = (int)(rr % G4);
    const int d  = (int)(rr / G4);
    float v = 0.f;
    if (k < Ks){
      const int u = nr >> 2, g = nr & 3;
      v = src[((long)d*G4 + g*HID + u)*Ks + k];
    }
    dst[i] = (_Float16)v;
  }
}

__global__ void prep_xpad(const float* __restrict__ x, _Float16* __restrict__ dst){
  const long n = (long)LSEQ*NB*DKP;
  for (long i = blockIdx.x*(long)blockDim.x + threadIdx.x; i < n; i += (long)gridDim.x*blockDim.x){
    const int k = (int)(i % DKP);
    const long rr = i / DKP;
    const int bb = (int)(rr % NB);
    const int t  = (int)(rr / NB);
    float v = 0.f;
    if (k < DIN) v = x[((long)bb*LSEQ + t)*DIN + k];   // x is [B][L][Din]
    dst[i] = (_Float16)v;
  }
}

__global__ void prep_bias(const float* bi0, const float* bh0, const float* bi1, const float* bh1,
                          float* o0, float* o1, int* bar0, int* barG, int* barS){
  const int tid = blockIdx.x*blockDim.x + threadIdx.x;
  for (int i = tid; i < 2*G4; i += gridDim.x*blockDim.x){
    const int nr = i % G4, d = i / G4;
    const int u = nr >> 2, g = nr & 3;
    const int old = d*G4 + g*HID + u;
    o0[i] = bi0[old] + bh0[old];
    o1[i] = bi1[old] + bh1[old];
  }
  for (int i = tid; i < 2*RST; i += gridDim.x*blockDim.x){ bar0[i] = 0; barS[i] = 0; }
  for (int i = tid; i < BARN;  i += gridDim.x*blockDim.x)  barG[i] = 0;
}

// ---- layer 0: grid 200 (100 WGs/dir). Fenced per-direction barrier per step
// (R0 protocol, dir-scoped). W_hh slice lives in LDS (fence-immune); h ring is
// NREP-replicated plain cached stores published by the barrier's release fence.
__global__ void __launch_bounds__(256, 1) layer0_kernel(P p){
  const int wg  = blockIdx.x;          // 0..199
  const int dir = wg / 100;
  const int wgd = wg % 100;
  const int wid = threadIdx.x >> 6;
  const int lane = threadIdx.x & 63;
  const int q = lane >> 4, c16 = lane & 15;
  const int wv = wgd*4 + wid;
  const int m  = wv >> 1;          // Mtile 0..199
  const int nt = wv & 1;
  const int b  = nt*16 + c16;
  const int ulocal = (wid >> 1)*4 + q;   // 0..7; WG owns units 8*wgd..8*wgd+7
  const int lw = (wid >> 1)*16 + c16;    // local weight row 0..31
  const int rowb = m*16 + q*4;
  const int rep = wgd & (NREP-1);
  float cst = 0.f;
  __shared__ _Float16 hT[2][8][32];
  __shared__ _Float16 wlds[32*WP];       // 51.7 KB: this WG's 32 W_hh gate rows

  // stage W_hh rows [dir*G4 + wgd*32 .. +32) into LDS once
  {
    const long base_row = (long)dir*G4 + wgd*32;
    for (int idx = threadIdx.x; idx < 3200; idx += 256){
      const int lr = idx / 100, c = idx % 100;
      *(h8v*)(wlds + lr*WP + c*8) = ldv(p.w0hh + (base_row + lr)*HID + c*8);
    }
  }
  __syncthreads();

  const long wih_row = ((long)dir*G4 + m*16 + c16)*DKP;
  int* bar = p.bar0 + dir*RST;
  const f4v bias = *(const f4v*)(p.bias0 + dir*G4 + rowb);

  for (int s = 0; s < LSEQ; ++s){
    const int t  = dir ? (LSEQ-1-s) : s;
    f4v acc = {0.f,0.f,0.f,0.f};
    f4v accl = {0.f,0.f,0.f,0.f};
    const long xb = ((long)t*NB + b)*DKP;
    #pragma unroll
    for (int kk = 0; kk < 2; ++kk){
      const int ko = kk*32 + q*8;
      acc = __builtin_amdgcn_mfma_f32_16x16x32_f16(
              ldv(p.w0ih + wih_row + ko), ldv(p.xp + xb + ko), acc, 0, 0, 0);
    }
    if (s > 0){
      const long hb = (((long)((s-1)&1)*NREP + rep)*NB + b)*H2 + dir*HID;
      const _Float16* rh = p.hr0h + hb;
      const _Float16* rl = p.hr0l + hb;
      const _Float16* wl = wlds + lw*WP;
      #pragma unroll
      for (int kk = 0; kk < 25; ++kk){
        const int ko = kk*32 + q*8;
        const h8v aw = *(const h8v*)(wl + ko);
        acc  = __builtin_amdgcn_mfma_f32_16x16x32_f16(aw, ldv(rh + ko), acc,  0, 0, 0);
        accl = __builtin_amdgcn_mfma_f32_16x16x32_f16(aw, ldv(rl + ko), accl, 0, 0, 0);
      }
    }
    const float gi = acc[0] + accl[0]*ISC + bias[0];
    const float gf = acc[1] + accl[1]*ISC + bias[1];
    const float gg = acc[2] + accl[2]*ISC + bias[2];
    const float go = acc[3] + accl[3]*ISC + bias[3];
    const float si = 1.f/(1.f + __expf(-gi));
    const float sf = 1.f/(1.f + __expf(-gf));
    const float so = 1.f/(1.f + __expf(-go));
    cst = sf*cst + si*tanhf(gg);
    const float h = so*tanhf(cst);
    const _Float16 hi = (_Float16)h;
    hT[0][ulocal][b] = hi;
    hT[1][ulocal][b] = (_Float16)((h - (float)hi)*SCAL);
    __syncthreads();
    {
      // publication: r = wave id (replica), part = hi/lo, bb = batch. Plain
      // cached stores — made visible by the barrier's release fence (R0 protocol).
      const int tid = threadIdx.x;
      const int r = tid >> 6, part = (tid >> 5) & 1, bb = tid & 31;
      h8v v;
      #pragma unroll
      for (int uu = 0; uu < 8; ++uu) v[uu] = hT[part][uu][bb];
      if (r == 0 && part == 0)
        *(h8v*)(p.h0 + (long)t*NB*H2 + (long)bb*H2 + dir*HID + wgd*8) = v;
      *(h8v*)((part ? p.hr0l : p.hr0h)
              + (((long)(s&1)*NREP + r)*NB + bb)*H2 + dir*HID + wgd*8) = v;
    }
    gbar_d(bar, s+1, wgd, 100);
  }
}

// ---- layer 1: grid 256. GEMM + logits phases verbatim R0 (full-grid fenced gbar
// at the 3 phase boundaries per chunk); recurrent steps use per-direction fenced
// barriers + LDS-resident W_hh + replicated ring.
__global__ void __launch_bounds__(256, 1) layer1_kernel(P p){
  const int wg  = blockIdx.x;
  const int dir = wg >> 7;
  const int wgd = wg & 127;
  const int wid = threadIdx.x >> 6;
  const int lane = threadIdx.x & 63;
  const int q = lane >> 4, c16 = lane & 15;
  const bool act = (wgd < 100);
  const int wv = wgd*4 + wid;
  const int m  = wv >> 1;
  const int nt = wv & 1;
  const int b  = nt*16 + c16;
  const int ulocal = (wid >> 1)*4 + q;
  const int lw = (wid >> 1)*16 + c16;
  const int rowb = m*16 + q*4;
  const int rep = wgd & (NREP-1);
  float cst = 0.f;
  __shared__ _Float16 hT[2][8][32];
  __shared__ _Float16 wlds[32*WP];
  int* barS = p.barS + dir*RST;
  const int Tc = p.Tc;
  const int SL = Tc + 1;
  const int ntN = Tc >> 2;
  const int tilesPerDir = 25*ntN;
  const int TILES = 2*tilesPerDir;
  int ep = 0;

  if (act){
    const long base_row = (long)dir*G4 + wgd*32;
    for (int idx = threadIdx.x; idx < 3200; idx += 256){
      const int lr = idx / 100, c = idx % 100;
      *(h8v*)(wlds + lr*WP + c*8) = ldv(p.w1hh + (base_row + lr)*HID + c*8);
    }
  }
  __syncthreads();

  for (int ci = 0; ci < p.nchunks; ++ci){
    // ---------- GEMM phase ----------
    for (int tile = blockIdx.x; tile < TILES; tile += gridDim.x){
      const int d   = tile / tilesPerDir;
      const int rem = tile % tilesPerDir;
      const int mi  = rem / ntN;
      const int ni  = rem % ntN;
      const int M0  = mi*128 + (wid >> 1)*64;
      const int N0  = ni*128 + (wid & 1)*64;
      f4v acc[4][4];
      #pragma unroll
      for (int ai=0; ai<4; ++ai)
        #pragma unroll
        for (int bi=0; bi<4; ++bi) acc[ai][bi] = (f4v){0,0,0,0};
      long hrow[4], arow[4];
      #pragma unroll
      for (int bi=0; bi<4; ++bi){
        const int n0 = N0 + bi*16;
        const int j  = n0 >> 5;
        const int bb = (n0 & 31) + c16;
        const int t  = d ? (LSEQ-1 - (ci*Tc + j)) : (ci*Tc + j);
        hrow[bi] = ((long)t*NB + bb)*H2;
      }
      #pragma unroll
      for (int ai=0; ai<4; ++ai) arow[ai] = ((long)d*G4 + M0 + ai*16 + c16)*H2;

      for (int kk = 0; kk < 50; ++kk){
        const int ko = kk*32 + q*8;
        h8v Ah[4], Bh[4];
        #pragma unroll
        for (int ai=0; ai<4; ++ai) Ah[ai] = ldv(p.w1ih + arow[ai] + ko);
        #pragma unroll
        for (int bi=0; bi<4; ++bi) Bh[bi] = ldv(p.h0 + hrow[bi] + ko);
        #pragma unroll
        for (int ai=0; ai<4; ++ai)
          #pragma unroll
          for (int bi=0; bi<4; ++bi)
            acc[ai][bi] = __builtin_amdgcn_mfma_f32_16x16x32_f16(Ah[ai], Bh[bi], acc[ai][bi], 0, 0, 0);
      }
      #pragma unroll
      for (int ai=0; ai<4; ++ai){
        const int row0 = M0 + ai*16 + q*4;
        const f4v bv = *(const f4v*)(p.bias1 + d*G4 + row0);
        #pragma unroll
        for (int bi=0; bi<4; ++bi){
          const int n0 = N0 + bi*16;
          const int j  = n0 >> 5;
          const int bb = (n0 & 31) + c16;
          f4v val = acc[ai][bi] + bv;
          *(f4v*)(p.gx1 + ((((long)d*Tc + j)*800 + (row0 >> 2))*NB + bb)*4) = val;
        }
      }
    }
    gbar(p.barG, ++ep);
    // ---------- recurrent steps (per-direction fenced barriers, active WGs) ----------
    if (act){
      for (int sl = 0; sl < Tc; ++sl){
        const int s  = ci*Tc + sl;
        f4v acc = *(const f4v*)(p.gx1 + ((((long)dir*Tc + sl)*800 + (rowb >> 2))*NB + b)*4);
        f4v accl = {0.f,0.f,0.f,0.f};
        if (s > 0){
          const long hb = (((long)((s-1)&1)*NREP + rep)*NB + b)*H2 + dir*HID;
          const _Float16* rh = p.r1h + hb;
          const _Float16* rl = p.r1l + hb;
          const _Float16* wl = wlds + lw*WP;
          #pragma unroll
          for (int kk = 0; kk < 25; ++kk){
            const int ko = kk*32 + q*8;
            const h8v aw = *(const h8v*)(wl + ko);
            acc  = __builtin_amdgcn_mfma_f32_16x16x32_f16(aw, ldv(rh + ko), acc,  0, 0, 0);
            accl = __builtin_amdgcn_mfma_f32_16x16x32_f16(aw, ldv(rl + ko), accl, 0, 0, 0);
          }
        }
        const float si = 1.f/(1.f + __expf(-(acc[0] + accl[0]*ISC)));
        const float sf = 1.f/(1.f + __expf(-(acc[1] + accl[1]*ISC)));
        const float so = 1.f/(1.f + __expf(-(acc[3] + accl[3]*ISC)));
        cst = sf*cst + si*tanhf(acc[2] + accl[2]*ISC);
        const float h = so*tanhf(cst);
        const _Float16 hi = (_Float16)h;
        hT[0][ulocal][b] = hi;
        hT[1][ulocal][b] = (_Float16)((h - (float)hi)*SCAL);
        __syncthreads();
        {
          const int tid = threadIdx.x;
          const int r = tid >> 6, part = (tid >> 5) & 1, bb = tid & 31;
          const int slot = s % SL;
          h8v v;
          #pragma unroll
          for (int uu = 0; uu < 8; ++uu) v[uu] = hT[part][uu][bb];
          if (r == 0)
            *(h8v*)((part ? p.h1wl : p.h1wh) + ((long)slot*NB + bb)*H2 + dir*HID + wgd*8) = v;
          *(h8v*)((part ? p.r1l : p.r1h)
                  + (((long)(s&1)*NREP + r)*NB + bb)*H2 + dir*HID + wgd*8) = v;
        }
        gbar_d(barS, s+1, wgd, 100);
      }
    }
    gbar(p.barG, ++ep);
    // ---------- logits phase ----------
    for (int pi = blockIdx.x; pi < 2*Tc; pi += gridDim.x){
      const int sl = pi >> 1, d = pi & 1;
      const int s  = ci*Tc + sl;
      const int t  = d ? (LSEQ-1-s) : s;
      const int slot = s % SL;
      const int bb = threadIdx.x & 31;
      const int k0 = threadIdx.x >> 5;
      const _Float16* hp  = p.h1wh + ((long)slot*NB + bb)*H2 + d*HID;
      const _Float16* hp2 = p.h1wl + ((long)slot*NB + bb)*H2 + d*HID;
      float* lp = (d ? p.logits1 : p.logits0) + ((long)t*NB + bb)*20;
      for (int k = k0; k < 20; k += 8){
        const float* wrow = p.w_lin + (long)k*H2 + d*HID;
        float acc2 = 0.f;
        for (int u = 0; u < HID; u += 8){
          h8v hv = ldv(hp + u);
          h8v lv = ldv(hp2 + u);
          #pragma unroll
          for (int j2 = 0; j2 < 8; ++j2)
            acc2 += ((float)hv[j2] + (float)lv[j2]*ISC) * wrow[u + j2];
        }
        lp[k] = acc2;
      }
    }
    gbar(p.barG, ++ep);
  }
}

// ---- head: logits -> softmax over BATCH axis -> angles -> dvec (reshape-scramble aware)
__global__ void head_kernel(P p){
  const int l = blockIdx.x;
  const int tid = threadIdx.x;
  __shared__ float lg[NB][20];
  __shared__ float sA[20][3], cA2[20][3];
  if (tid < 60){
    const float a = p.alphabet[tid];
    sA[tid/3][tid%3]  = sinf(a);
    cA2[tid/3][tid%3] = cosf(a);
  }
  for (int i = tid; i < NB*20; i += blockDim.x){
    const int bb = i / 20, k = i % 20;
    lg[bb][k] = p.logits0[((long)l*NB + bb)*20 + k] +
                p.logits1[((long)l*NB + bb)*20 + k] + p.b_lin[k];
  }
  __syncthreads();
  if (tid < 20){
    float mx = -1e30f;
    for (int bb=0; bb<NB; ++bb) mx = fmaxf(mx, lg[bb][tid]);
    float sum = 0.f;
    for (int bb=0; bb<NB; ++bb) sum += expf(lg[bb][tid] - mx);
    const float inv = 1.f/sum;
    for (int bb=0; bb<NB; ++bb) lg[bb][tid] = expf(lg[bb][tid] - mx)*inv;
  }
  __syncthreads();
  if (tid < 96){
    const int bb = tid/3, dd = tid%3;     // angle source (ang[l][bb][dd])
    const int pp = tid >> 5;              // scan row within step-triple
    const int j  = tid & 31;              // NeRF lane (column of phis)
    float ss = 0.f, cc = 0.f;
    #pragma unroll
    for (int k=0; k<20; ++k){ ss += lg[bb][k]*sA[k][dd]; cc += lg[bb][k]*cA2[k][dd]; }
    const float phi = atan2f(ss, cc);
    const float BL[3] = {145.801f, 152.326f, 132.868f};
    const float BA[3] = {2.124f, 1.941f, 2.028f};
    const float r = BL[pp], th = BA[pp];
    float* dv = p.dvec + ((long)(l*3 + pp)*NB + j)*4;
    dv[0] = -r*cosf(th);
    dv[1] = r*sinf(th)*cosf(phi);
    dv[2] = r*sinf(th)*sinf(phi);
  }
}

// ---- NeRF extension: strictly sequential, 1 lane per scan column.
__global__ void nerf_kernel(P p){
  const int bb = threadIdx.x;
  if (bb >= NB) return;
  float ax=0.f,ay=0.f,az=0.f, bx=100.f,by=0.f,bz=0.f, cx=200.f,cy=100.f,cz=0.f;
  for (int i = 0; i < 3*LSEQ; ++i){
    const float* dv = p.dvec + ((long)i*NB + bb)*4;
    const float d0=dv[0], d1=dv[1], d2=dv[2];
    float ux=cx-bx, uy=cy-by, uz=cz-bz;
    float inv = 1.f/(sqrtf(ux*ux+uy*uy+uz*uz)+1e-12f);
    ux*=inv; uy*=inv; uz*=inv;
    const float px=bx-ax, py=by-ay, pz=bz-az;
    float nx=py*uz-pz*uy, ny=pz*ux-px*uz, nz=px*uy-py*ux;
    inv = 1.f/(sqrtf(nx*nx+ny*ny+nz*nz)+1e-12f);
    nx*=inv; ny*=inv; nz*=inv;
    const float mx=ny*uz-nz*uy, my=nz*ux-nx*uz, mz=nx*uy-ny*ux;
    const float Dx = cx + d0*ux + d1*mx + d2*nx;
    const float Dy = cy + d0*uy + d1*my + d2*ny;
    const float Dz = cz + d0*uz + d1*mz + d2*nz;
    float* o = p.out + ((long)i*NB + bb)*3;
    o[0]=Dx; o[1]=Dy; o[2]=Dz;
    ax=bx; ay=by; az=bz;
    bx=cx; by=cy; bz=cz;
    cx=Dx; cy=Dy; cz=Dz;
  }
}

extern "C" void kernel_launch(void* const* d_in, const int* in_sizes, int n_in,
                              void* d_out, int out_size, void* d_ws, size_t ws_size,
                              hipStream_t stream){
  P p{};
  p.x      = (const float*)d_in[0];
  p.w_ih0  = (const float*)d_in[1];
  p.w_hh0  = (const float*)d_in[2];
  p.b_ih0  = (const float*)d_in[3];
  p.b_hh0  = (const float*)d_in[4];
  p.w_ih1  = (const float*)d_in[5];
  p.w_hh1  = (const float*)d_in[6];
  p.b_ih1  = (const float*)d_in[7];
  p.b_hh1  = (const float*)d_in[8];
  p.w_lin  = (const float*)d_in[9];
  p.b_lin  = (const float*)d_in[10];
  p.alphabet = (const float*)d_in[11];
  p.out    = (float*)d_out;

  char* base = (char*)d_ws;
  size_t off = 0;
  auto alloc = [&](size_t bytes)->void*{
    void* r = base + off;
    off = (off + bytes + 255) & ~(size_t)255;
    return r;
  };
  p.h0      = (_Float16*)alloc((size_t)LSEQ*NB*H2*2);        // 71.68 MB
  p.hr0h    = (_Float16*)alloc((size_t)2*NREP*NB*H2*2);      // 0.82 MB
  p.hr0l    = (_Float16*)alloc((size_t)2*NREP*NB*H2*2);
  p.r1h     = (_Float16*)alloc((size_t)2*NREP*NB*H2*2);
  p.r1l     = (_Float16*)alloc((size_t)2*NREP*NB*H2*2);
  p.w0hh    = (_Float16*)alloc((size_t)2*G4*HID*2);          // 10.24 MB
  p.w1hh    = (_Float16*)alloc((size_t)2*G4*HID*2);          // 10.24 MB
  p.w1ih    = (_Float16*)alloc((size_t)2*G4*H2*2);           // 20.48 MB
  p.w0ih    = (_Float16*)alloc((size_t)2*G4*DKP*2);
  p.xp      = (_Float16*)alloc((size_t)LSEQ*NB*DKP*2);
  p.bias0   = (float*)alloc((size_t)2*G4*4);
  p.bias1   = (float*)alloc((size_t)2*G4*4);
  p.logits0 = (float*)alloc((size_t)LSEQ*NB*20*4);
  p.logits1 = (float*)alloc((size_t)LSEQ*NB*20*4);
  p.dvec    = (float*)alloc((size_t)3*LSEQ*NB*4*4);
  p.bar0    = (int*)alloc((size_t)2*RST*4);
  p.barG    = (int*)alloc((size_t)BARN*4);
  p.barS    = (int*)alloc((size_t)2*RST*4);

  const int cands[5] = {140, 100, 28, 20, 4};   // must divide 700 and be %4==0
  int Tc = 4;
  for (int i = 0; i < 5; ++i){
    const size_t need = off
      + (size_t)2*cands[i]*800*NB*4*4 + 256
      + (size_t)2*(cands[i]+1)*NB*H2*2 + 512;
    if (need <= ws_size){ Tc = cands[i]; break; }
  }
  p.gx1  = (float*)alloc((size_t)2*Tc*800*NB*4*4);
  p.h1wh = (_Float16*)alloc((size_t)(Tc+1)*NB*H2*2);
  p.h1wl = (_Float16*)alloc((size_t)(Tc+1)*NB*H2*2);
  p.Tc = Tc;
  p.nchunks = LSEQ / Tc;

  hipLaunchKernelGGL(prep_w, dim3(1024), dim3(256), 0, stream, p.w_hh0, p.w0hh, HID, HID);
  hipLaunchKernelGGL(prep_w, dim3(1024), dim3(256), 0, stream, p.w_hh1, p.w1hh, HID, HID);
  hipLaunchKernelGGL(prep_w, dim3(2048), dim3(256), 0, stream, p.w_ih1, p.w1ih, H2, H2);
  hipLaunchKernelGGL(prep_w, dim3(256),  dim3(256), 0, stream, p.w_ih0, p.w0ih, DIN, DKP);
  hipLaunchKernelGGL(prep_xpad, dim3(512), dim3(256), 0, stream, p.x, p.xp);
  hipLaunchKernelGGL(prep_bias, dim3(32), dim3(256), 0, stream,
                     p.b_ih0, p.b_hh0, p.b_ih1, p.b_hh1, p.bias0, p.bias1,
                     p.bar0, p.barG, p.barS);

  void* args[] = { &p };
  hipLaunchCooperativeKernel((void*)layer0_kernel, dim3(200), dim3(256), args, 0, stream);
  hipLaunchCooperativeKernel((void*)layer1_kernel, dim3(256), dim3(256), args, 0, stream);
  hipLaunchKernelGGL(head_kernel, dim3(LSEQ), dim3(256), 0, stream, p);
  hipLaunchKernelGGL(nerf_kernel, dim3(1), dim3(64), 0, stream, p);
}

// Round 5
// 29245.209 us; speedup vs baseline: 1.2089x; 1.0007x over previous
//
#include <hip/hip_runtime.h>

#define LSEQ 700
#define NB   32
#define DIN  41
#define HID  800
#define G4   3200   // 4*H gate rows
#define H2   1600   // 2*H
#define DKP  64     // Din padded to MFMA K granularity
#define NREP 4      // h-ring replicas (LLC line hotspot mitigation)
#define WP   808    // LDS weight row stride (f16): 1616B -> 2-way bank alias (free)

#define SCAL 2048.f
#define ISC  (1.f/2048.f)

// full-grid gbar region: 256 arrive flags (64B stride) + 64 go words (64B stride)
#define GOOFF (256*16)
#define BARN  (256*16 + 64*16)
// per-direction step-barrier region: 128 arrive flags (64B stride)
#define RST   (192*16)

typedef _Float16 h8v __attribute__((ext_vector_type(8)));  // 8 f16 = 4 VGPRs (MFMA A/B frag)
typedef float    f4v __attribute__((ext_vector_type(4)));

struct P {
  const float *x, *w_ih0, *w_hh0, *b_ih0, *b_hh0;
  const float *w_ih1, *w_hh1, *b_ih1, *b_hh1;
  const float *w_lin, *b_lin, *alphabet;
  _Float16 *h0;                    // [t][b][dir*800+u] f16 hi — full history (layer1 GEMM input)
  _Float16 *hr0h, *hr0l;           // layer0 depth-2 ring x NREP replicas [slot][rep][b][dir*800+u]
  _Float16 *r1h,  *r1l;            // layer1 depth-2 ring x NREP replicas
  _Float16 *h1wh, *h1wl;           // layer1 SL ring [slot][b][dir*800+u] (logits reads after gbar)
  _Float16 *w0hh, *w1hh;           // [dir][permrow 4u+g][800]
  _Float16 *w1ih;                  // [dir][permrow][1600]
  _Float16 *w0ih;                  // [dir][permrow][64]
  _Float16 *xp;                    // [t][b][64]
  float *bias0, *bias1;            // [dir][permrow]
  float *logits0, *logits1;        // [t][b][20]
  float *dvec;                     // [3L][j][4]
  float *gx1;                      // [d][sl][unit][b][4] f32
  float *out;
  int *bar0;                       // layer0 per-dir step-barrier regions [2][RST]
  int *barG;                       // layer1 full-grid gbar (phase boundaries)
  int *barS;                       // layer1 per-dir step-barrier regions [2][RST]
  int Tc, nchunks;
};

__device__ __forceinline__ h8v ldv(const _Float16* p_){ return *(const h8v*)p_; }

// Full-grid fenced barrier (VERBATIM R0/R3 semantics) — layer1 phase boundaries.
__device__ __forceinline__ void gbar(int* bar, int ep){
  __syncthreads();
  if (threadIdx.x == 0){
    __builtin_amdgcn_fence(__ATOMIC_RELEASE, "agent");   // L2 writeback to coherence point
    __hip_atomic_store(&bar[blockIdx.x*16], ep, __ATOMIC_RELAXED, __HIP_MEMORY_SCOPE_AGENT);
  }
  if (blockIdx.x == 0){
    for (int i = threadIdx.x; i < (int)gridDim.x; i += blockDim.x)
      while (__hip_atomic_load(&bar[i*16], __ATOMIC_RELAXED, __HIP_MEMORY_SCOPE_AGENT) < ep)
        __builtin_amdgcn_s_sleep(1);
    __syncthreads();
    if (threadIdx.x < 64)
      __hip_atomic_store(&bar[GOOFF + threadIdx.x*16], ep, __ATOMIC_RELAXED, __HIP_MEMORY_SCOPE_AGENT);
  } else {
    if (threadIdx.x == 0){
      while (__hip_atomic_load(&bar[GOOFF + (blockIdx.x & 63)*16], __ATOMIC_RELAXED, __HIP_MEMORY_SCOPE_AGENT) < ep)
        __builtin_amdgcn_s_sleep(1);
    }
  }
  __syncthreads();
  __builtin_amdgcn_fence(__ATOMIC_ACQUIRE, "agent");     // invalidate caches: fresh loads
}

// Per-direction ALL-TO-ALL fenced step barrier. Same release/acquire fences as
// R3's gbar_d, but no hub: each WG stores its arrive flag after the release
// fence, then threads i<n poll all n flags directly. Removes the go-broadcast
// LLC round trip and hub serialization; semantics identical (every WG verifies
// all arrived before its acquire invalidate).
__device__ __forceinline__ void abar(int* bar, int ep, int wgd, int n){
  __syncthreads();                       // all waves' vmcnt drained (stores in L2)
  if (threadIdx.x == 0){
    __builtin_amdgcn_fence(__ATOMIC_RELEASE, "agent");   // wbl2: push to LLC
    __hip_atomic_store(&bar[wgd*16], ep, __ATOMIC_RELAXED, __HIP_MEMORY_SCOPE_AGENT);
  }
  if (threadIdx.x < n){
    while (__hip_atomic_load(&bar[threadIdx.x*16], __ATOMIC_RELAXED, __HIP_MEMORY_SCOPE_AGENT) < ep)
      __builtin_amdgcn_s_sleep(1);
  }
  __syncthreads();
  __builtin_amdgcn_fence(__ATOMIC_ACQUIRE, "agent");     // invalidate: fresh ring reads
}

// ---- prep: permuted-row f16 weights. newrow = 4*u + gate (gate order i,f,g,o)
__global__ void prep_w(const float* __restrict__ src, _Float16* __restrict__ dst,
                       int Ks, int Kd){
  const long n = (long)2*G4*Kd;
  for (long i = blockIdx.x*(long)blockDim.x + threadIdx.x; i < n; i += (long)gridDim.x*blockDim.x){
    const int k  = (int)(i % Kd);
    const long rr = i / Kd;
    const int nr = (int)(rr % G4);
    const int d  = (int)(rr / G4);
    float v = 0.f;
    if (k < Ks){
      const int u = nr >> 2, g = nr & 3;
      v = src[((long)d*G4 + g*HID + u)*Ks + k];
    }
    dst[i] = (_Float16)v;
  }
}

__global__ void prep_xpad(const float* __restrict__ x, _Float16* __restrict__ dst){
  const long n = (long)LSEQ*NB*DKP;
  for (long i = blockIdx.x*(long)blockDim.x + threadIdx.x; i < n; i += (long)gridDim.x*blockDim.x){
    const int k = (int)(i % DKP);
    const long rr = i / DKP;
    const int bb = (int)(rr % NB);
    const int t  = (int)(rr / NB);
    float v = 0.f;
    if (k < DIN) v = x[((long)bb*LSEQ + t)*DIN + k];   // x is [B][L][Din]
    dst[i] = (_Float16)v;
  }
}

__global__ void prep_bias(const float* bi0, const float* bh0, const float* bi1, const float* bh1,
                          float* o0, float* o1, int* bar0, int* barG, int* barS){
  const int tid = blockIdx.x*blockDim.x + threadIdx.x;
  for (int i = tid; i < 2*G4; i += gridDim.x*blockDim.x){
    const int nr = i % G4, d = i / G4;
    const int u = nr >> 2, g = nr & 3;
    const int old = d*G4 + g*HID + u;
    o0[i] = bi0[old] + bh0[old];
    o1[i] = bi1[old] + bh1[old];
  }
  for (int i = tid; i < 2*RST; i += gridDim.x*blockDim.x){ bar0[i] = 0; barS[i] = 0; }
  for (int i = tid; i < BARN;  i += gridDim.x*blockDim.x)  barG[i] = 0;
}

// ---- layer 0: grid 100, 512 threads (8 waves), 50 WGs/dir. Per step:
// [h-MFMA from ring] -> activations -> publish ring (NREP replicas, plain
// cached stores) -> prefetch next x-GEMM (immutable inputs, carried in regs
// across the fence) -> all-to-all fenced barrier (50 flags/dir).
// W_hh slice (64 rows, 102.4 KB) lives in LDS: immune to acquire invalidates.
__global__ void __launch_bounds__(512, 1) layer0_kernel(P p){
  const int wg  = blockIdx.x;          // 0..99
  const int dir = wg / 50;
  const int wgd = wg % 50;
  const int wid = threadIdx.x >> 6;    // 0..7
  const int lane = threadIdx.x & 63;
  const int q = lane >> 4, c16 = lane & 15;
  const int wv = wgd*8 + wid;          // 0..399
  const int m  = wv >> 1;              // Mtile 0..199
  const int nt = wv & 1;
  const int b  = nt*16 + c16;
  const int ulocal = (wid >> 1)*4 + q; // 0..15: WG owns units 16*wgd..+16
  const int lw = (wid >> 1)*16 + c16;  // local weight row 0..63
  const int rowb = m*16 + q*4;
  const int rep = wgd & (NREP-1);
  float cst = 0.f;
  __shared__ _Float16 hT[2][16][32];
  __shared__ _Float16 wlds[64*WP];     // 103.4 KB: this WG's 64 W_hh gate rows

  // stage W_hh rows [dir*G4 + wgd*64 .. +64) into LDS once
  {
    const long base_row = (long)dir*G4 + wgd*64;
    for (int idx = threadIdx.x; idx < 6400; idx += 512){
      const int lr = idx / 100, c = idx % 100;
      *(h8v*)(wlds + lr*WP + c*8) = ldv(p.w0hh + (base_row + lr)*HID + c*8);
    }
  }
  __syncthreads();

  const long wih_row = ((long)dir*G4 + m*16 + c16)*DKP;
  int* bar = p.bar0 + dir*RST;
  const f4v bias = *(const f4v*)(p.bias0 + dir*G4 + rowb);

  // prologue: x-GEMM for s=0
  f4v xacc = {0.f,0.f,0.f,0.f};
  {
    const int t0 = dir ? (LSEQ-1) : 0;
    const long xb = ((long)t0*NB + b)*DKP;
    #pragma unroll
    for (int kk = 0; kk < 2; ++kk){
      const int ko = kk*32 + q*8;
      xacc = __builtin_amdgcn_mfma_f32_16x16x32_f16(
               ldv(p.w0ih + wih_row + ko), ldv(p.xp + xb + ko), xacc, 0, 0, 0);
    }
  }

  for (int s = 0; s < LSEQ; ++s){
    const int t  = dir ? (LSEQ-1-s) : s;
    f4v acc = xacc;                    // x contribution, same FP order as R3
    f4v accl = {0.f,0.f,0.f,0.f};
    if (s > 0){
      const long hb = (((long)((s-1)&1)*NREP + rep)*NB + b)*H2 + dir*HID;
      const _Float16* rh = p.hr0h + hb;
      const _Float16* rl = p.hr0l + hb;
      const _Float16* wl = wlds + lw*WP;
      #pragma unroll
      for (int kk = 0; kk < 25; ++kk){
        const int ko = kk*32 + q*8;
        const h8v aw = *(const h8v*)(wl + ko);
        acc  = __builtin_amdgcn_mfma_f32_16x16x32_f16(aw, ldv(rh + ko), acc,  0, 0, 0);
        accl = __builtin_amdgcn_mfma_f32_16x16x32_f16(aw, ldv(rl + ko), accl, 0, 0, 0);
      }
    }
    const float gi = acc[0] + accl[0]*ISC + bias[0];
    const float gf = acc[1] + accl[1]*ISC + bias[1];
    const float gg = acc[2] + accl[2]*ISC + bias[2];
    const float go = acc[3] + accl[3]*ISC + bias[3];
    const float si = 1.f/(1.f + __expf(-gi));
    const float sf = 1.f/(1.f + __expf(-gf));
    const float so = 1.f/(1.f + __expf(-go));
    cst = sf*cst + si*tanhf(gg);
    const float h = so*tanhf(cst);
    const _Float16 hi = (_Float16)h;
    hT[0][ulocal][b] = hi;
    hT[1][ulocal][b] = (_Float16)((h - (float)hi)*SCAL);
    __syncthreads();
    {
      // publish: each of 512 threads writes one 16B replica share.
      // r = replica, part = hi/lo, ub = unit-block (8 units), bb = batch.
      const int tid = threadIdx.x;
      const int r = tid >> 7;
      const int rem = tid & 127;
      const int part = rem >> 6;
      const int ub = (rem >> 5) & 1;
      const int bb = rem & 31;
      h8v v;
      #pragma unroll
      for (int uu = 0; uu < 8; ++uu) v[uu] = hT[part][ub*8 + uu][bb];
      if (r == 0 && part == 0)
        *(h8v*)(p.h0 + (long)t*NB*H2 + (long)bb*H2 + dir*HID + wgd*16 + ub*8) = v;
      *(h8v*)((part ? p.hr0l : p.hr0h)
              + (((long)(s&1)*NREP + r)*NB + bb)*H2 + dir*HID + wgd*16 + ub*8) = v;
    }
    // prefetch next step's x-GEMM before the barrier (xp/w0ih immutable;
    // result carried in registers across the fences)
    f4v xn = {0.f,0.f,0.f,0.f};
    if (s + 1 < LSEQ){
      const int t2 = dir ? (LSEQ-2-s) : (s+1);
      const long xb2 = ((long)t2*NB + b)*DKP;
      #pragma unroll
      for (int kk = 0; kk < 2; ++kk){
        const int ko = kk*32 + q*8;
        xn = __builtin_amdgcn_mfma_f32_16x16x32_f16(
               ldv(p.w0ih + wih_row + ko), ldv(p.xp + xb2 + ko), xn, 0, 0, 0);
      }
    }
    xacc = xn;
    abar(bar, s+1, wgd, 50);
  }
}

// ---- layer 1: grid 256, 4 waves (GEMM tile structure unchanged). GEMM + logits
// phases verbatim R3 with full-grid fenced gbar; recurrent steps use the
// all-to-all per-dir barrier + LDS-resident W_hh + gx1 prefetch.
__global__ void __launch_bounds__(256, 1) layer1_kernel(P p){
  const int wg  = blockIdx.x;
  const int dir = wg >> 7;
  const int wgd = wg & 127;
  const int wid = threadIdx.x >> 6;
  const int lane = threadIdx.x & 63;
  const int q = lane >> 4, c16 = lane & 15;
  const bool act = (wgd < 100);
  const int wv = wgd*4 + wid;
  const int m  = wv >> 1;
  const int nt = wv & 1;
  const int b  = nt*16 + c16;
  const int ulocal = (wid >> 1)*4 + q;
  const int lw = (wid >> 1)*16 + c16;
  const int rowb = m*16 + q*4;
  const int rep = wgd & (NREP-1);
  float cst = 0.f;
  __shared__ _Float16 hT[2][8][32];
  __shared__ _Float16 wlds[32*WP];
  int* barS = p.barS + dir*RST;
  const int Tc = p.Tc;
  const int SL = Tc + 1;
  const int ntN = Tc >> 2;
  const int tilesPerDir = 25*ntN;
  const int TILES = 2*tilesPerDir;
  int ep = 0;

  if (act){
    const long base_row = (long)dir*G4 + wgd*32;
    for (int idx = threadIdx.x; idx < 3200; idx += 256){
      const int lr = idx / 100, c = idx % 100;
      *(h8v*)(wlds + lr*WP + c*8) = ldv(p.w1hh + (base_row + lr)*HID + c*8);
    }
  }
  __syncthreads();

  for (int ci = 0; ci < p.nchunks; ++ci){
    // ---------- GEMM phase ----------
    for (int tile = blockIdx.x; tile < TILES; tile += gridDim.x){
      const int d   = tile / tilesPerDir;
      const int rem = tile % tilesPerDir;
      const int mi  = rem / ntN;
      const int ni  = rem % ntN;
      const int M0  = mi*128 + (wid >> 1)*64;
      const int N0  = ni*128 + (wid & 1)*64;
      f4v acc[4][4];
      #pragma unroll
      for (int ai=0; ai<4; ++ai)
        #pragma unroll
        for (int bi=0; bi<4; ++bi) acc[ai][bi] = (f4v){0,0,0,0};
      long hrow[4], arow[4];
      #pragma unroll
      for (int bi=0; bi<4; ++bi){
        const int n0 = N0 + bi*16;
        const int j  = n0 >> 5;
        const int bb = (n0 & 31) + c16;
        const int t  = d ? (LSEQ-1 - (ci*Tc + j)) : (ci*Tc + j);
        hrow[bi] = ((long)t*NB + bb)*H2;
      }
      #pragma unroll
      for (int ai=0; ai<4; ++ai) arow[ai] = ((long)d*G4 + M0 + ai*16 + c16)*H2;

      for (int kk = 0; kk < 50; ++kk){
        const int ko = kk*32 + q*8;
        h8v Ah[4], Bh[4];
        #pragma unroll
        for (int ai=0; ai<4; ++ai) Ah[ai] = ldv(p.w1ih + arow[ai] + ko);
        #pragma unroll
        for (int bi=0; bi<4; ++bi) Bh[bi] = ldv(p.h0 + hrow[bi] + ko);
        #pragma unroll
        for (int ai=0; ai<4; ++ai)
          #pragma unroll
          for (int bi=0; bi<4; ++bi)
            acc[ai][bi] = __builtin_amdgcn_mfma_f32_16x16x32_f16(Ah[ai], Bh[bi], acc[ai][bi], 0, 0, 0);
      }
      #pragma unroll
      for (int ai=0; ai<4; ++ai){
        const int row0 = M0 + ai*16 + q*4;
        const f4v bv = *(const f4v*)(p.bias1 + d*G4 + row0);
        #pragma unroll
        for (int bi=0; bi<4; ++bi){
          const int n0 = N0 + bi*16;
          const int j  = n0 >> 5;
          const int bb = (n0 & 31) + c16;
          f4v val = acc[ai][bi] + bv;
          *(f4v*)(p.gx1 + ((((long)d*Tc + j)*800 + (row0 >> 2))*NB + bb)*4) = val;
        }
      }
    }
    gbar(p.barG, ++ep);
    // ---------- recurrent steps (all-to-all barrier, active WGs) ----------
    if (act){
      f4v accNext = *(const f4v*)(p.gx1 + ((((long)dir*Tc + 0)*800 + (rowb >> 2))*NB + b)*4);
      for (int sl = 0; sl < Tc; ++sl){
        const int s  = ci*Tc + sl;
        f4v acc = accNext;
        f4v accl = {0.f,0.f,0.f,0.f};
        if (s > 0){
          const long hb = (((long)((s-1)&1)*NREP + rep)*NB + b)*H2 + dir*HID;
          const _Float16* rh = p.r1h + hb;
          const _Float16* rl = p.r1l + hb;
          const _Float16* wl = wlds + lw*WP;
          #pragma unroll
          for (int kk = 0; kk < 25; ++kk){
            const int ko = kk*32 + q*8;
            const h8v aw = *(const h8v*)(wl + ko);
            acc  = __builtin_amdgcn_mfma_f32_16x16x32_f16(aw, ldv(rh + ko), acc,  0, 0, 0);
            accl = __builtin_amdgcn_mfma_f32_16x16x32_f16(aw, ldv(rl + ko), accl, 0, 0, 0);
          }
        }
        const float si = 1.f/(1.f + __expf(-(acc[0] + accl[0]*ISC)));
        const float sf = 1.f/(1.f + __expf(-(acc[1] + accl[1]*ISC)));
        const float so = 1.f/(1.f + __expf(-(acc[3] + accl[3]*ISC)));
        cst = sf*cst + si*tanhf(acc[2] + accl[2]*ISC);
        const float h = so*tanhf(cst);
        const _Float16 hi = (_Float16)h;
        hT[0][ulocal][b] = hi;
        hT[1][ulocal][b] = (_Float16)((h - (float)hi)*SCAL);
        __syncthreads();
        {
          const int tid = threadIdx.x;
          const int r = tid >> 6, part = (tid >> 5) & 1, bb = tid & 31;
          const int slot = s % SL;
          h8v v;
          #pragma unroll
          for (int uu = 0; uu < 8; ++uu) v[uu] = hT[part][uu][bb];
          if (r == 0)
            *(h8v*)((part ? p.h1wl : p.h1wh) + ((long)slot*NB + bb)*H2 + dir*HID + wgd*8) = v;
          *(h8v*)((part ? p.r1l : p.r1h)
                  + (((long)(s&1)*NREP + r)*NB + bb)*H2 + dir*HID + wgd*8) = v;
        }
        // prefetch next gx1 (immutable within chunk) before the barrier
        if (sl + 1 < Tc)
          accNext = *(const f4v*)(p.gx1 + ((((long)dir*Tc + sl+1)*800 + (rowb >> 2))*NB + b)*4);
        abar(barS, s+1, wgd, 100);
      }
    }
    gbar(p.barG, ++ep);
    // ---------- logits phase ----------
    for (int pi = blockIdx.x; pi < 2*Tc; pi += gridDim.x){
      const int sl = pi >> 1, d = pi & 1;
      const int s  = ci*Tc + sl;
      const int t  = d ? (LSEQ-1-s) : s;
      const int slot = s % SL;
      const int bb = threadIdx.x & 31;
      const int k0 = threadIdx.x >> 5;
      const _Float16* hp  = p.h1wh + ((long)slot*NB + bb)*H2 + d*HID;
      const _Float16* hp2 = p.h1wl + ((long)slot*NB + bb)*H2 + d*HID;
      float* lp = (d ? p.logits1 : p.logits0) + ((long)t*NB + bb)*20;
      for (int k = k0; k < 20; k += 8){
        const float* wrow = p.w_lin + (long)k*H2 + d*HID;
        float acc2 = 0.f;
        for (int u = 0; u < HID; u += 8){
          h8v hv = ldv(hp + u);
          h8v lv = ldv(hp2 + u);
          #pragma unroll
          for (int j2 = 0; j2 < 8; ++j2)
            acc2 += ((float)hv[j2] + (float)lv[j2]*ISC) * wrow[u + j2];
        }
        lp[k] = acc2;
      }
    }
    gbar(p.barG, ++ep);
  }
}

// ---- head: logits -> softmax over BATCH axis -> angles -> dvec (reshape-scramble aware)
__global__ void head_kernel(P p){
  const int l = blockIdx.x;
  const int tid = threadIdx.x;
  __shared__ float lg[NB][20];
  __shared__ float sA[20][3], cA2[20][3];
  if (tid < 60){
    const float a = p.alphabet[tid];
    sA[tid/3][tid%3]  = sinf(a);
    cA2[tid/3][tid%3] = cosf(a);
  }
  for (int i = tid; i < NB*20; i += blockDim.x){
    const int bb = i / 20, k = i % 20;
    lg[bb][k] = p.logits0[((long)l*NB + bb)*20 + k] +
                p.logits1[((long)l*NB + bb)*20 + k] + p.b_lin[k];
  }
  __syncthreads();
  if (tid < 20){
    float mx = -1e30f;
    for (int bb=0; bb<NB; ++bb) mx = fmaxf(mx, lg[bb][tid]);
    float sum = 0.f;
    for (int bb=0; bb<NB; ++bb) sum += expf(lg[bb][tid] - mx);
    const float inv = 1.f/sum;
    for (int bb=0; bb<NB; ++bb) lg[bb][tid] = expf(lg[bb][tid] - mx)*inv;
  }
  __syncthreads();
  if (tid < 96){
    const int bb = tid/3, dd = tid%3;     // angle source (ang[l][bb][dd])
    const int pp = tid >> 5;              // scan row within step-triple
    const int j  = tid & 31;              // NeRF lane (column of phis)
    float ss = 0.f, cc = 0.f;
    #pragma unroll
    for (int k=0; k<20; ++k){ ss += lg[bb][k]*sA[k][dd]; cc += lg[bb][k]*cA2[k][dd]; }
    const float phi = atan2f(ss, cc);
    const float BL[3] = {145.801f, 152.326f, 132.868f};
    const float BA[3] = {2.124f, 1.941f, 2.028f};
    const float r = BL[pp], th = BA[pp];
    float* dv = p.dvec + ((long)(l*3 + pp)*NB + j)*4;
    dv[0] = -r*cosf(th);
    dv[1] = r*sinf(th)*cosf(phi);
    dv[2] = r*sinf(th)*sinf(phi);
  }
}

// ---- NeRF extension: strictly sequential, 1 lane per scan column.
__global__ void nerf_kernel(P p){
  const int bb = threadIdx.x;
  if (bb >= NB) return;
  float ax=0.f,ay=0.f,az=0.f, bx=100.f,by=0.f,bz=0.f, cx=200.f,cy=100.f,cz=0.f;
  for (int i = 0; i < 3*LSEQ; ++i){
    const float* dv = p.dvec + ((long)i*NB + bb)*4;
    const float d0=dv[0], d1=dv[1], d2=dv[2];
    float ux=cx-bx, uy=cy-by, uz=cz-bz;
    float inv = 1.f/(sqrtf(ux*ux+uy*uy+uz*uz)+1e-12f);
    ux*=inv; uy*=inv; uz*=inv;
    const float px=bx-ax, py=by-ay, pz=bz-az;
    float nx=py*uz-pz*uy, ny=pz*ux-px*uz, nz=px*uy-py*ux;
    inv = 1.f/(sqrtf(nx*nx+ny*ny+nz*nz)+1e-12f);
    nx*=inv; ny*=inv; nz*=inv;
    const float mx=ny*uz-nz*uy, my=nz*ux-nx*uz, mz=nx*uy-ny*ux;
    const float Dx = cx + d0*ux + d1*mx + d2*nx;
    const float Dy = cy + d0*uy + d1*my + d2*ny;
    const float Dz = cz + d0*uz + d1*mz + d2*nz;
    float* o = p.out + ((long)i*NB + bb)*3;
    o[0]=Dx; o[1]=Dy; o[2]=Dz;
    ax=bx; ay=by; az=bz;
    bx=cx; by=cy; bz=cz;
    cx=Dx; cy=Dy; cz=Dz;
  }
}

extern "C" void kernel_launch(void* const* d_in, const int* in_sizes, int n_in,
                              void* d_out, int out_size, void* d_ws, size_t ws_size,
                              hipStream_t stream){
  P p{};
  p.x      = (const float*)d_in[0];
  p.w_ih0  = (const float*)d_in[1];
  p.w_hh0  = (const float*)d_in[2];
  p.b_ih0  = (const float*)d_in[3];
  p.b_hh0  = (const float*)d_in[4];
  p.w_ih1  = (const float*)d_in[5];
  p.w_hh1  = (const float*)d_in[6];
  p.b_ih1  = (const float*)d_in[7];
  p.b_hh1  = (const float*)d_in[8];
  p.w_lin  = (const float*)d_in[9];
  p.b_lin  = (const float*)d_in[10];
  p.alphabet = (const float*)d_in[11];
  p.out    = (float*)d_out;

  char* base = (char*)d_ws;
  size_t off = 0;
  auto alloc = [&](size_t bytes)->void*{
    void* r = base + off;
    off = (off + bytes + 255) & ~(size_t)255;
    return r;
  };
  p.h0      = (_Float16*)alloc((size_t)LSEQ*NB*H2*2);        // 71.68 MB
  p.hr0h    = (_Float16*)alloc((size_t)2*NREP*NB*H2*2);      // 0.82 MB
  p.hr0l    = (_Float16*)alloc((size_t)2*NREP*NB*H2*2);
  p.r1h     = (_Float16*)alloc((size_t)2*NREP*NB*H2*2);
  p.r1l     = (_Float16*)alloc((size_t)2*NREP*NB*H2*2);
  p.w0hh    = (_Float16*)alloc((size_t)2*G4*HID*2);          // 10.24 MB
  p.w1hh    = (_Float16*)alloc((size_t)2*G4*HID*2);          // 10.24 MB
  p.w1ih    = (_Float16*)alloc((size_t)2*G4*H2*2);           // 20.48 MB
  p.w0ih    = (_Float16*)alloc((size_t)2*G4*DKP*2);
  p.xp      = (_Float16*)alloc((size_t)LSEQ*NB*DKP*2);
  p.bias0   = (float*)alloc((size_t)2*G4*4);
  p.bias1   = (float*)alloc((size_t)2*G4*4);
  p.logits0 = (float*)alloc((size_t)LSEQ*NB*20*4);
  p.logits1 = (float*)alloc((size_t)LSEQ*NB*20*4);
  p.dvec    = (float*)alloc((size_t)3*LSEQ*NB*4*4);
  p.bar0    = (int*)alloc((size_t)2*RST*4);
  p.barG    = (int*)alloc((size_t)BARN*4);
  p.barS    = (int*)alloc((size_t)2*RST*4);

  const int cands[5] = {140, 100, 28, 20, 4};   // must divide 700 and be %4==0
  int Tc = 4;
  for (int i = 0; i < 5; ++i){
    const size_t need = off
      + (size_t)2*cands[i]*800*NB*4*4 + 256
      + (size_t)2*(cands[i]+1)*NB*H2*2 + 512;
    if (need <= ws_size){ Tc = cands[i]; break; }
  }
  p.gx1  = (float*)alloc((size_t)2*Tc*800*NB*4*4);
  p.h1wh = (_Float16*)alloc((size_t)(Tc+1)*NB*H2*2);
  p.h1wl = (_Float16*)alloc((size_t)(Tc+1)*NB*H2*2);
  p.Tc = Tc;
  p.nchunks = LSEQ / Tc;

  hipLaunchKernelGGL(prep_w, dim3(1024), dim3(256), 0, stream, p.w_hh0, p.w0hh, HID, HID);
  hipLaunchKernelGGL(prep_w, dim3(1024), dim3(256), 0, stream, p.w_hh1, p.w1hh, HID, HID);
  hipLaunchKernelGGL(prep_w, dim3(2048), dim3(256), 0, stream, p.w_ih1, p.w1ih, H2, H2);
  hipLaunchKernelGGL(prep_w, dim3(256),  dim3(256), 0, stream, p.w_ih0, p.w0ih, DIN, DKP);
  hipLaunchKernelGGL(prep_xpad, dim3(512), dim3(256), 0, stream, p.x, p.xp);
  hipLaunchKernelGGL(prep_bias, dim3(32), dim3(256), 0, stream,
                     p.b_ih0, p.b_hh0, p.b_ih1, p.b_hh1, p.bias0, p.bias1,
                     p.bar0, p.barG, p.barS);

  void* args[] = { &p };
  hipLaunchCooperativeKernel((void*)layer0_kernel, dim3(100), dim3(512), args, 0, stream);
  hipLaunchCooperativeKernel((void*)layer1_kernel, dim3(256), dim3(256), args, 0, stream);
  hipLaunchKernelGGL(head_kernel, dim3(LSEQ), dim3(256), 0, stream, p);
  hipLaunchKernelGGL(nerf_kernel, dim3(1), dim3(64), 0, stream, p);
}

// Round 7
// 24688.313 us; speedup vs baseline: 1.4320x; 1.1846x over previous
//
#include <hip/hip_runtime.h>

#define LSEQ 700
#define NB   32
#define DIN  41
#define HID  800
#define G4   3200   // 4*H gate rows
#define H2   1600   // 2*H
#define DKP  64     // Din padded to MFMA K granularity
#define NREP 4      // h-ring replicas (LLC line hotspot mitigation)
#define WP   808    // LDS weight row stride (f16): 1616B -> 2-way bank alias (free)

#define SCAL 2048.f
#define ISC  (1.f/2048.f)

// full-grid gbar region: 256 arrive flags (64B stride) + 64 go words (64B stride)
#define GOOFF (256*16)
#define BARN  (256*16 + 64*16)
// per-direction step-barrier region: 128 arrive flags (64B stride)
#define RST   (192*16)

typedef _Float16 h8v __attribute__((ext_vector_type(8)));  // 8 f16 = 4 VGPRs (MFMA A/B frag)
typedef float    f4v __attribute__((ext_vector_type(4)));

struct P {
  const float *x, *w_ih0, *w_hh0, *b_ih0, *b_hh0;
  const float *w_ih1, *w_hh1, *b_ih1, *b_hh1;
  const float *w_lin, *b_lin, *alphabet;
  _Float16 *h0;                    // [t][b][dir*800+u] f16 hi — full history (layer1 GEMM input)
  _Float16 *hr0h, *hr0l;           // layer0 depth-2 ring x NREP replicas [slot][rep][b][dir*800+u]
  _Float16 *r1h,  *r1l;            // layer1 depth-2 ring x NREP replicas
  _Float16 *h1wh, *h1wl;           // layer1 SL ring [slot][b][dir*800+u] (logits reads after gbar)
  _Float16 *w0hh, *w1hh;           // [dir][permrow 4u+g][800]
  _Float16 *w1ih;                  // [dir][permrow][1600]
  _Float16 *w0ih;                  // [dir][permrow][64]
  _Float16 *xp;                    // [t][b][64]
  float *bias0, *bias1;            // [dir][permrow]
  float *logits0, *logits1;        // [t][b][20]
  float *dvec;                     // [3L][j][4]
  float *gx1;                      // [d][sl][unit][b][4] f32
  float *out;
  int *bar0;                       // layer0 per-dir step-barrier regions [2][RST]
  int *barG;                       // layer1 full-grid gbar (phase boundaries)
  int *barS;                       // layer1 per-dir step-barrier regions [2][RST]
  int Tc, nchunks;
};

__device__ __forceinline__ h8v ldv(const _Float16* p_){ return *(const h8v*)p_; }

// Coherent flag poll: agent-scope RMW executes AT the LLC (per-XCD L2s are
// non-coherent, so the RMW cannot resolve locally) -> every poll reads the
// coherence point directly, immune to the stale-L2-line problem that makes
// relaxed-load spins eviction-bound. fetch_add(0) is idempotent and atomic at
// the LLC slice, so it is race-safe against the producer's flag store.
__device__ __forceinline__ int poll(int* f){
  return __hip_atomic_fetch_add(f, 0, __ATOMIC_RELAXED, __HIP_MEMORY_SCOPE_AGENT);
}

// Full-grid fenced barrier — layer1 phase boundaries. RMW polls; acquire fence
// executed by ONE wave per WG (L1 is CU-shared, L2 is XCD-shared, so one
// buffer_inv covers all waves), second __syncthreads gates the other waves.
__device__ __forceinline__ void gbar(int* bar, int ep){
  __syncthreads();
  if (threadIdx.x == 0){
    __builtin_amdgcn_fence(__ATOMIC_RELEASE, "agent");   // L2 writeback to coherence point
    __hip_atomic_store(&bar[blockIdx.x*16], ep, __ATOMIC_RELAXED, __HIP_MEMORY_SCOPE_AGENT);
  }
  if (blockIdx.x == 0){
    for (int i = threadIdx.x; i < (int)gridDim.x; i += blockDim.x)
      while (poll(&bar[i*16]) < ep)
        __builtin_amdgcn_s_sleep(1);
    __syncthreads();
    if (threadIdx.x < 64)
      __hip_atomic_store(&bar[GOOFF + threadIdx.x*16], ep, __ATOMIC_RELAXED, __HIP_MEMORY_SCOPE_AGENT);
  } else {
    if (threadIdx.x == 0){
      while (poll(&bar[GOOFF + (blockIdx.x & 63)*16]) < ep)
        __builtin_amdgcn_s_sleep(1);
    }
  }
  __syncthreads();
  if (threadIdx.x < 64)
    __builtin_amdgcn_fence(__ATOMIC_ACQUIRE, "agent");   // single buffer_inv per WG
  __syncthreads();
}

// Per-direction ALL-TO-ALL fenced step barrier (RMW polls; single-wave acquire).
__device__ __forceinline__ void abar(int* bar, int ep, int wgd, int n){
  __syncthreads();                       // all waves' vmcnt drained (stores in L2)
  if (threadIdx.x == 0){
    __builtin_amdgcn_fence(__ATOMIC_RELEASE, "agent");   // wbl2: push to LLC
    __hip_atomic_store(&bar[wgd*16], ep, __ATOMIC_RELAXED, __HIP_MEMORY_SCOPE_AGENT);
  }
  if (threadIdx.x < n){
    while (poll(&bar[threadIdx.x*16]) < ep)
      __builtin_amdgcn_s_sleep(1);
  }
  __syncthreads();
  if (threadIdx.x < 64)
    __builtin_amdgcn_fence(__ATOMIC_ACQUIRE, "agent");   // single buffer_inv per WG
  __syncthreads();
}

// ---- prep: permuted-row f16 weights. newrow = 4*u + gate (gate order i,f,g,o)
__global__ void prep_w(const float* __restrict__ src, _Float16* __restrict__ dst,
                       int Ks, int Kd){
  const long n = (long)2*G4*Kd;
  for (long i = blockIdx.x*(long)blockDim.x + threadIdx.x; i < n; i += (long)gridDim.x*blockDim.x){
    const int k  = (int)(i % Kd);
    const long rr = i / Kd;
    const int nr = (int)(rr % G4);
    const int d  = (int)(rr / G4);
    float v = 0.f;
    if (k < Ks){
      const int u = nr >> 2, g = nr & 3;
      v = src[((long)d*G4 + g*HID + u)*Ks + k];
    }
    dst[i] = (_Float16)v;
  }
}

__global__ void prep_xpad(const float* __restrict__ x, _Float16* __restrict__ dst){
  const long n = (long)LSEQ*NB*DKP;
  for (long i = blockIdx.x*(long)blockDim.x + threadIdx.x; i < n; i += (long)gridDim.x*blockDim.x){
    const int k = (int)(i % DKP);
    const long rr = i / DKP;
    const int bb = (int)(rr % NB);
    const int t  = (int)(rr / NB);
    float v = 0.f;
    if (k < DIN) v = x[((long)bb*LSEQ + t)*DIN + k];   // x is [B][L][Din]
    dst[i] = (_Float16)v;
  }
}

__global__ void prep_bias(const float* bi0, const float* bh0, const float* bi1, const float* bh1,
                          float* o0, float* o1, int* bar0, int* barG, int* barS){
  const int tid = blockIdx.x*blockDim.x + threadIdx.x;
  for (int i = tid; i < 2*G4; i += gridDim.x*blockDim.x){
    const int nr = i % G4, d = i / G4;
    const int u = nr >> 2, g = nr & 3;
    const int old = d*G4 + g*HID + u;
    o0[i] = bi0[old] + bh0[old];
    o1[i] = bi1[old] + bh1[old];
  }
  for (int i = tid; i < 2*RST; i += gridDim.x*blockDim.x){ bar0[i] = 0; barS[i] = 0; }
  for (int i = tid; i < BARN;  i += gridDim.x*blockDim.x)  barG[i] = 0;
}

// ---- layer 0: grid 100, 512 threads (8 waves), 50 WGs/dir. R5-verbatim compute;
// barrier uses RMW polls + single-wave acquire.
__global__ void __launch_bounds__(512, 1) layer0_kernel(P p){
  const int wg  = blockIdx.x;          // 0..99
  const int dir = wg / 50;
  const int wgd = wg % 50;
  const int wid = threadIdx.x >> 6;    // 0..7
  const int lane = threadIdx.x & 63;
  const int q = lane >> 4, c16 = lane & 15;
  const int wv = wgd*8 + wid;          // 0..399
  const int m  = wv >> 1;              // Mtile 0..199
  const int nt = wv & 1;
  const int b  = nt*16 + c16;
  const int ulocal = (wid >> 1)*4 + q; // 0..15: WG owns units 16*wgd..+16
  const int lw = (wid >> 1)*16 + c16;  // local weight row 0..63
  const int rowb = m*16 + q*4;
  const int rep = wgd & (NREP-1);
  float cst = 0.f;
  __shared__ _Float16 hT[2][16][32];
  __shared__ _Float16 wlds[64*WP];     // 103.4 KB: this WG's 64 W_hh gate rows

  // stage W_hh rows [dir*G4 + wgd*64 .. +64) into LDS once
  {
    const long base_row = (long)dir*G4 + wgd*64;
    for (int idx = threadIdx.x; idx < 6400; idx += 512){
      const int lr = idx / 100, c = idx % 100;
      *(h8v*)(wlds + lr*WP + c*8) = ldv(p.w0hh + (base_row + lr)*HID + c*8);
    }
  }
  __syncthreads();

  const long wih_row = ((long)dir*G4 + m*16 + c16)*DKP;
  int* bar = p.bar0 + dir*RST;
  const f4v bias = *(const f4v*)(p.bias0 + dir*G4 + rowb);

  // prologue: x-GEMM for s=0
  f4v xacc = {0.f,0.f,0.f,0.f};
  {
    const int t0 = dir ? (LSEQ-1) : 0;
    const long xb = ((long)t0*NB + b)*DKP;
    #pragma unroll
    for (int kk = 0; kk < 2; ++kk){
      const int ko = kk*32 + q*8;
      xacc = __builtin_amdgcn_mfma_f32_16x16x32_f16(
               ldv(p.w0ih + wih_row + ko), ldv(p.xp + xb + ko), xacc, 0, 0, 0);
    }
  }

  for (int s = 0; s < LSEQ; ++s){
    const int t  = dir ? (LSEQ-1-s) : s;
    f4v acc = xacc;                    // x contribution, same FP order as R3
    f4v accl = {0.f,0.f,0.f,0.f};
    if (s > 0){
      const long hb = (((long)((s-1)&1)*NREP + rep)*NB + b)*H2 + dir*HID;
      const _Float16* rh = p.hr0h + hb;
      const _Float16* rl = p.hr0l + hb;
      const _Float16* wl = wlds + lw*WP;
      #pragma unroll
      for (int kk = 0; kk < 25; ++kk){
        const int ko = kk*32 + q*8;
        const h8v aw = *(const h8v*)(wl + ko);
        acc  = __builtin_amdgcn_mfma_f32_16x16x32_f16(aw, ldv(rh + ko), acc,  0, 0, 0);
        accl = __builtin_amdgcn_mfma_f32_16x16x32_f16(aw, ldv(rl + ko), accl, 0, 0, 0);
      }
    }
    const float gi = acc[0] + accl[0]*ISC + bias[0];
    const float gf = acc[1] + accl[1]*ISC + bias[1];
    const float gg = acc[2] + accl[2]*ISC + bias[2];
    const float go = acc[3] + accl[3]*ISC + bias[3];
    const float si = 1.f/(1.f + __expf(-gi));
    const float sf = 1.f/(1.f + __expf(-gf));
    const float so = 1.f/(1.f + __expf(-go));
    cst = sf*cst + si*tanhf(gg);
    const float h = so*tanhf(cst);
    const _Float16 hi = (_Float16)h;
    hT[0][ulocal][b] = hi;
    hT[1][ulocal][b] = (_Float16)((h - (float)hi)*SCAL);
    __syncthreads();
    {
      // publish: each of 512 threads writes one 16B replica share.
      const int tid = threadIdx.x;
      const int r = tid >> 7;
      const int rem = tid & 127;
      const int part = rem >> 6;
      const int ub = (rem >> 5) & 1;
      const int bb = rem & 31;
      h8v v;
      #pragma unroll
      for (int uu = 0; uu < 8; ++uu) v[uu] = hT[part][ub*8 + uu][bb];
      if (r == 0 && part == 0)
        *(h8v*)(p.h0 + (long)t*NB*H2 + (long)bb*H2 + dir*HID + wgd*16 + ub*8) = v;
      *(h8v*)((part ? p.hr0l : p.hr0h)
              + (((long)(s&1)*NREP + r)*NB + bb)*H2 + dir*HID + wgd*16 + ub*8) = v;
    }
    // prefetch next step's x-GEMM before the barrier
    f4v xn = {0.f,0.f,0.f,0.f};
    if (s + 1 < LSEQ){
      const int t2 = dir ? (LSEQ-2-s) : (s+1);
      const long xb2 = ((long)t2*NB + b)*DKP;
      #pragma unroll
      for (int kk = 0; kk < 2; ++kk){
        const int ko = kk*32 + q*8;
        xn = __builtin_amdgcn_mfma_f32_16x16x32_f16(
               ldv(p.w0ih + wih_row + ko), ldv(p.xp + xb2 + ko), xn, 0, 0, 0);
      }
    }
    xacc = xn;
    abar(bar, s+1, wgd, 50);
  }
}

// ---- layer 1: grid 256, 4 waves. R5-verbatim; RMW polls + single-wave acquire.
__global__ void __launch_bounds__(256, 1) layer1_kernel(P p){
  const int wg  = blockIdx.x;
  const int dir = wg >> 7;
  const int wgd = wg & 127;
  const int wid = threadIdx.x >> 6;
  const int lane = threadIdx.x & 63;
  const int q = lane >> 4, c16 = lane & 15;
  const bool act = (wgd < 100);
  const int wv = wgd*4 + wid;
  const int m  = wv >> 1;
  const int nt = wv & 1;
  const int b  = nt*16 + c16;
  const int ulocal = (wid >> 1)*4 + q;
  const int lw = (wid >> 1)*16 + c16;
  const int rowb = m*16 + q*4;
  const int rep = wgd & (NREP-1);
  float cst = 0.f;
  __shared__ _Float16 hT[2][8][32];
  __shared__ _Float16 wlds[32*WP];
  int* barS = p.barS + dir*RST;
  const int Tc = p.Tc;
  const int SL = Tc + 1;
  const int ntN = Tc >> 2;
  const int tilesPerDir = 25*ntN;
  const int TILES = 2*tilesPerDir;
  int ep = 0;

  if (act){
    const long base_row = (long)dir*G4 + wgd*32;
    for (int idx = threadIdx.x; idx < 3200; idx += 256){
      const int lr = idx / 100, c = idx % 100;
      *(h8v*)(wlds + lr*WP + c*8) = ldv(p.w1hh + (base_row + lr)*HID + c*8);
    }
  }
  __syncthreads();

  for (int ci = 0; ci < p.nchunks; ++ci){
    // ---------- GEMM phase ----------
    for (int tile = blockIdx.x; tile < TILES; tile += gridDim.x){
      const int d   = tile / tilesPerDir;
      const int rem = tile % tilesPerDir;
      const int mi  = rem / ntN;
      const int ni  = rem % ntN;
      const int M0  = mi*128 + (wid >> 1)*64;
      const int N0  = ni*128 + (wid & 1)*64;
      f4v acc[4][4];
      #pragma unroll
      for (int ai=0; ai<4; ++ai)
        #pragma unroll
        for (int bi=0; bi<4; ++bi) acc[ai][bi] = (f4v){0,0,0,0};
      long hrow[4], arow[4];
      #pragma unroll
      for (int bi=0; bi<4; ++bi){
        const int n0 = N0 + bi*16;
        const int j  = n0 >> 5;
        const int bb = (n0 & 31) + c16;
        const int t  = d ? (LSEQ-1 - (ci*Tc + j)) : (ci*Tc + j);
        hrow[bi] = ((long)t*NB + bb)*H2;
      }
      #pragma unroll
      for (int ai=0; ai<4; ++ai) arow[ai] = ((long)d*G4 + M0 + ai*16 + c16)*H2;

      for (int kk = 0; kk < 50; ++kk){
        const int ko = kk*32 + q*8;
        h8v Ah[4], Bh[4];
        #pragma unroll
        for (int ai=0; ai<4; ++ai) Ah[ai] = ldv(p.w1ih + arow[ai] + ko);
        #pragma unroll
        for (int bi=0; bi<4; ++bi) Bh[bi] = ldv(p.h0 + hrow[bi] + ko);
        #pragma unroll
        for (int ai=0; ai<4; ++ai)
          #pragma unroll
          for (int bi=0; bi<4; ++bi)
            acc[ai][bi] = __builtin_amdgcn_mfma_f32_16x16x32_f16(Ah[ai], Bh[bi], acc[ai][bi], 0, 0, 0);
      }
      #pragma unroll
      for (int ai=0; ai<4; ++ai){
        const int row0 = M0 + ai*16 + q*4;
        const f4v bv = *(const f4v*)(p.bias1 + d*G4 + row0);
        #pragma unroll
        for (int bi=0; bi<4; ++bi){
          const int n0 = N0 + bi*16;
          const int j  = n0 >> 5;
          const int bb = (n0 & 31) + c16;
          f4v val = acc[ai][bi] + bv;
          *(f4v*)(p.gx1 + ((((long)d*Tc + j)*800 + (row0 >> 2))*NB + bb)*4) = val;
        }
      }
    }
    gbar(p.barG, ++ep);
    // ---------- recurrent steps (all-to-all barrier, active WGs) ----------
    if (act){
      f4v accNext = *(const f4v*)(p.gx1 + ((((long)dir*Tc + 0)*800 + (rowb >> 2))*NB + b)*4);
      for (int sl = 0; sl < Tc; ++sl){
        const int s  = ci*Tc + sl;
        f4v acc = accNext;
        f4v accl = {0.f,0.f,0.f,0.f};
        if (s > 0){
          const long hb = (((long)((s-1)&1)*NREP + rep)*NB + b)*H2 + dir*HID;
          const _Float16* rh = p.r1h + hb;
          const _Float16* rl = p.r1l + hb;
          const _Float16* wl = wlds + lw*WP;
          #pragma unroll
          for (int kk = 0; kk < 25; ++kk){
            const int ko = kk*32 + q*8;
            const h8v aw = *(const h8v*)(wl + ko);
            acc  = __builtin_amdgcn_mfma_f32_16x16x32_f16(aw, ldv(rh + ko), acc,  0, 0, 0);
            accl = __builtin_amdgcn_mfma_f32_16x16x32_f16(aw, ldv(rl + ko), accl, 0, 0, 0);
          }
        }
        const float si = 1.f/(1.f + __expf(-(acc[0] + accl[0]*ISC)));
        const float sf = 1.f/(1.f + __expf(-(acc[1] + accl[1]*ISC)));
        const float so = 1.f/(1.f + __expf(-(acc[3] + accl[3]*ISC)));
        cst = sf*cst + si*tanhf(acc[2] + accl[2]*ISC);
        const float h = so*tanhf(cst);
        const _Float16 hi = (_Float16)h;
        hT[0][ulocal][b] = hi;
        hT[1][ulocal][b] = (_Float16)((h - (float)hi)*SCAL);
        __syncthreads();
        {
          const int tid = threadIdx.x;
          const int r = tid >> 6, part = (tid >> 5) & 1, bb = tid & 31;
          const int slot = s % SL;
          h8v v;
          #pragma unroll
          for (int uu = 0; uu < 8; ++uu) v[uu] = hT[part][uu][bb];
          if (r == 0)
            *(h8v*)((part ? p.h1wl : p.h1wh) + ((long)slot*NB + bb)*H2 + dir*HID + wgd*8) = v;
          *(h8v*)((part ? p.r1l : p.r1h)
                  + (((long)(s&1)*NREP + r)*NB + bb)*H2 + dir*HID + wgd*8) = v;
        }
        // prefetch next gx1 (immutable within chunk) before the barrier
        if (sl + 1 < Tc)
          accNext = *(const f4v*)(p.gx1 + ((((long)dir*Tc + sl+1)*800 + (rowb >> 2))*NB + b)*4);
        abar(barS, s+1, wgd, 100);
      }
    }
    gbar(p.barG, ++ep);
    // ---------- logits phase ----------
    for (int pi = blockIdx.x; pi < 2*Tc; pi += gridDim.x){
      const int sl = pi >> 1, d = pi & 1;
      const int s  = ci*Tc + sl;
      const int t  = d ? (LSEQ-1-s) : s;
      const int slot = s % SL;
      const int bb = threadIdx.x & 31;
      const int k0 = threadIdx.x >> 5;
      const _Float16* hp  = p.h1wh + ((long)slot*NB + bb)*H2 + d*HID;
      const _Float16* hp2 = p.h1wl + ((long)slot*NB + bb)*H2 + d*HID;
      float* lp = (d ? p.logits1 : p.logits0) + ((long)t*NB + bb)*20;
      for (int k = k0; k < 20; k += 8){
        const float* wrow = p.w_lin + (long)k*H2 + d*HID;
        float acc2 = 0.f;
        for (int u = 0; u < HID; u += 8){
          h8v hv = ldv(hp + u);
          h8v lv = ldv(hp2 + u);
          #pragma unroll
          for (int j2 = 0; j2 < 8; ++j2)
            acc2 += ((float)hv[j2] + (float)lv[j2]*ISC) * wrow[u + j2];
        }
        lp[k] = acc2;
      }
    }
    gbar(p.barG, ++ep);
  }
}

// ---- head: logits -> softmax over BATCH axis -> angles -> dvec (reshape-scramble aware)
__global__ void head_kernel(P p){
  const int l = blockIdx.x;
  const int tid = threadIdx.x;
  __shared__ float lg[NB][20];
  __shared__ float sA[20][3], cA2[20][3];
  if (tid < 60){
    const float a = p.alphabet[tid];
    sA[tid/3][tid%3]  = sinf(a);
    cA2[tid/3][tid%3] = cosf(a);
  }
  for (int i = tid; i < NB*20; i += blockDim.x){
    const int bb = i / 20, k = i % 20;
    lg[bb][k] = p.logits0[((long)l*NB + bb)*20 + k] +
                p.logits1[((long)l*NB + bb)*20 + k] + p.b_lin[k];
  }
  __syncthreads();
  if (tid < 20){
    float mx = -1e30f;
    for (int bb=0; bb<NB; ++bb) mx = fmaxf(mx, lg[bb][tid]);
    float sum = 0.f;
    for (int bb=0; bb<NB; ++bb) sum += expf(lg[bb][tid] - mx);
    const float inv = 1.f/sum;
    for (int bb=0; bb<NB; ++bb) lg[bb][tid] = expf(lg[bb][tid] - mx)*inv;
  }
  __syncthreads();
  if (tid < 96){
    const int bb = tid/3, dd = tid%3;     // angle source (ang[l][bb][dd])
    const int pp = tid >> 5;              // scan row within step-triple
    const int j  = tid & 31;              // NeRF lane (column of phis)
    float ss = 0.f, cc = 0.f;
    #pragma unroll
    for (int k=0; k<20; ++k){ ss += lg[bb][k]*sA[k][dd]; cc += lg[bb][k]*cA2[k][dd]; }
    const float phi = atan2f(ss, cc);
    const float BL[3] = {145.801f, 152.326f, 132.868f};
    const float BA[3] = {2.124f, 1.941f, 2.028f};
    const float r = BL[pp], th = BA[pp];
    float* dv = p.dvec + ((long)(l*3 + pp)*NB + j)*4;
    dv[0] = -r*cosf(th);
    dv[1] = r*sinf(th)*cosf(phi);
    dv[2] = r*sinf(th)*sinf(phi);
  }
}

// ---- NeRF extension: strictly sequential, 1 lane per scan column.
__global__ void nerf_kernel(P p){
  const int bb = threadIdx.x;
  if (bb >= NB) return;
  float ax=0.f,ay=0.f,az=0.f, bx=100.f,by=0.f,bz=0.f, cx=200.f,cy=100.f,cz=0.f;
  for (int i = 0; i < 3*LSEQ; ++i){
    const float* dv = p.dvec + ((long)i*NB + bb)*4;
    const float d0=dv[0], d1=dv[1], d2=dv[2];
    float ux=cx-bx, uy=cy-by, uz=cz-bz;
    float inv = 1.f/(sqrtf(ux*ux+uy*uy+uz*uz)+1e-12f);
    ux*=inv; uy*=inv; uz*=inv;
    const float px=bx-ax, py=by-ay, pz=bz-az;
    float nx=py*uz-pz*uy, ny=pz*ux-px*uz, nz=px*uy-py*ux;
    inv = 1.f/(sqrtf(nx*nx+ny*ny+nz*nz)+1e-12f);
    nx*=inv; ny*=inv; nz*=inv;
    const float mx=ny*uz-nz*uy, my=nz*ux-nx*uz, mz=nx*uy-ny*ux;
    const float Dx = cx + d0*ux + d1*mx + d2*nx;
    const float Dy = cy + d0*uy + d1*my + d2*ny;
    const float Dz = cz + d0*uz + d1*mz + d2*nz;
    float* o = p.out + ((long)i*NB + bb)*3;
    o[0]=Dx; o[1]=Dy; o[2]=Dz;
    ax=bx; ay=by; az=bz;
    bx=cx; by=cy; bz=cz;
    cx=Dx; cy=Dy; cz=Dz;
  }
}

extern "C" void kernel_launch(void* const* d_in, const int* in_sizes, int n_in,
                              void* d_out, int out_size, void* d_ws, size_t ws_size,
                              hipStream_t stream){
  P p{};
  p.x      = (const float*)d_in[0];
  p.w_ih0  = (const float*)d_in[1];
  p.w_hh0  = (const float*)d_in[2];
  p.b_ih0  = (const float*)d_in[3];
  p.b_hh0  = (const float*)d_in[4];
  p.w_ih1  = (const float*)d_in[5];
  p.w_hh1  = (const float*)d_in[6];
  p.b_ih1  = (const float*)d_in[7];
  p.b_hh1  = (const float*)d_in[8];
  p.w_lin  = (const float*)d_in[9];
  p.b_lin  = (const float*)d_in[10];
  p.alphabet = (const float*)d_in[11];
  p.out    = (float*)d_out;

  char* base = (char*)d_ws;
  size_t off = 0;
  auto alloc = [&](size_t bytes)->void*{
    void* r = base + off;
    off = (off + bytes + 255) & ~(size_t)255;
    return r;
  };
  p.h0      = (_Float16*)alloc((size_t)LSEQ*NB*H2*2);        // 71.68 MB
  p.hr0h    = (_Float16*)alloc((size_t)2*NREP*NB*H2*2);      // 0.82 MB
  p.hr0l    = (_Float16*)alloc((size_t)2*NREP*NB*H2*2);
  p.r1h     = (_Float16*)alloc((size_t)2*NREP*NB*H2*2);
  p.r1l     = (_Float16*)alloc((size_t)2*NREP*NB*H2*2);
  p.w0hh    = (_Float16*)alloc((size_t)2*G4*HID*2);          // 10.24 MB
  p.w1hh    = (_Float16*)alloc((size_t)2*G4*HID*2);          // 10.24 MB
  p.w1ih    = (_Float16*)alloc((size_t)2*G4*H2*2);           // 20.48 MB
  p.w0ih    = (_Float16*)alloc((size_t)2*G4*DKP*2);
  p.xp      = (_Float16*)alloc((size_t)LSEQ*NB*DKP*2);
  p.bias0   = (float*)alloc((size_t)2*G4*4);
  p.bias1   = (float*)alloc((size_t)2*G4*4);
  p.logits0 = (float*)alloc((size_t)LSEQ*NB*20*4);
  p.logits1 = (float*)alloc((size_t)LSEQ*NB*20*4);
  p.dvec    = (float*)alloc((size_t)3*LSEQ*NB*4*4);
  p.bar0    = (int*)alloc((size_t)2*RST*4);
  p.barG    = (int*)alloc((size_t)BARN*4);
  p.barS    = (int*)alloc((size_t)2*RST*4);

  const int cands[5] = {140, 100, 28, 20, 4};   // must divide 700 and be %4==0
  int Tc = 4;
  for (int i = 0; i < 5; ++i){
    const size_t need = off
      + (size_t)2*cands[i]*800*NB*4*4 + 256
      + (size_t)2*(cands[i]+1)*NB*H2*2 + 512;
    if (need <= ws_size){ Tc = cands[i]; break; }
  }
  p.gx1  = (float*)alloc((size_t)2*Tc*800*NB*4*4);
  p.h1wh = (_Float16*)alloc((size_t)(Tc+1)*NB*H2*2);
  p.h1wl = (_Float16*)alloc((size_t)(Tc+1)*NB*H2*2);
  p.Tc = Tc;
  p.nchunks = LSEQ / Tc;

  hipLaunchKernelGGL(prep_w, dim3(1024), dim3(256), 0, stream, p.w_hh0, p.w0hh, HID, HID);
  hipLaunchKernelGGL(prep_w, dim3(1024), dim3(256), 0, stream, p.w_hh1, p.w1hh, HID, HID);
  hipLaunchKernelGGL(prep_w, dim3(2048), dim3(256), 0, stream, p.w_ih1, p.w1ih, H2, H2);
  hipLaunchKernelGGL(prep_w, dim3(256),  dim3(256), 0, stream, p.w_ih0, p.w0ih, DIN, DKP);
  hipLaunchKernelGGL(prep_xpad, dim3(512), dim3(256), 0, stream, p.x, p.xp);
  hipLaunchKernelGGL(prep_bias, dim3(32), dim3(256), 0, stream,
                     p.b_ih0, p.b_hh0, p.b_ih1, p.b_hh1, p.bias0, p.bias1,
                     p.bar0, p.barG, p.barS);

  void* args[] = { &p };
  hipLaunchCooperativeKernel((void*)layer0_kernel, dim3(100), dim3(512), args, 0, stream);
  hipLaunchCooperativeKernel((void*)layer1_kernel, dim3(256), dim3(256), args, 0, stream);
  hipLaunchKernelGGL(head_kernel, dim3(LSEQ), dim3(256), 0, stream, p);
  hipLaunchKernelGGL(nerf_kernel, dim3(1), dim3(64), 0, stream, p);
}

// Round 8
// 22598.645 us; speedup vs baseline: 1.5644x; 1.0925x over previous
//
#include <hip/hip_runtime.h>

#define LSEQ 700
#define NB   32
#define DIN  41
#define HID  800
#define G4   3200   // 4*H gate rows
#define H2   1600   // 2*H
#define DKP  64     // Din padded to MFMA K granularity
#define NREP 4      // h-ring replicas (LLC line hotspot mitigation)
#define WP   808    // LDS weight row stride (f16): 1616B -> 2-way bank alias (free)

#define SCAL 2048.f
#define ISC  (1.f/2048.f)

// full-grid gbar region: 256 arrive flags (64B stride) + 64 go words (64B stride)
#define GOOFF (256*16)
#define BARN  (256*16 + 64*16)
// per-direction step-barrier region: 128 arrive flags (64B stride)
#define RST   (192*16)

typedef _Float16 h8v __attribute__((ext_vector_type(8)));  // 8 f16 = 4 VGPRs (MFMA A/B frag)
typedef float    f4v __attribute__((ext_vector_type(4)));
typedef unsigned long long u64;

struct P {
  const float *x, *w_ih0, *w_hh0, *b_ih0, *b_hh0;
  const float *w_ih1, *w_hh1, *b_ih1, *b_hh1;
  const float *w_lin, *b_lin, *alphabet;
  _Float16 *h0;                    // [t][b][dir*800+u] f16 hi — full history (layer1 GEMM input)
  _Float16 *hr0h, *hr0l;           // layer0 depth-2 ring x NREP replicas [slot][rep][b][dir*800+u]
  _Float16 *r1h,  *r1l;            // layer1 depth-2 ring x NREP replicas
  _Float16 *h1wh, *h1wl;           // layer1 SL ring [slot][b][dir*800+u] (logits reads after gbar)
  _Float16 *w0hh, *w1hh;           // [dir][permrow 4u+g][800]
  _Float16 *w1ih;                  // [dir][permrow][1600]
  _Float16 *w0ih;                  // [dir][permrow][64]
  _Float16 *xp;                    // [t][b][64]
  float *bias0, *bias1;            // [dir][permrow]
  float *logits0, *logits1;        // [t][b][20]
  float *dvec;                     // [3L][j][4]
  float *gx1;                      // [d][sl][unit][b][4] f32
  float *out;
  int *bar0;                       // layer0 per-dir step-barrier regions [2][RST]
  int *barG;                       // layer1 full-grid gbar (phase boundaries)
  int *barS;                       // layer1 per-dir step-barrier regions [2][RST]
  int Tc, nchunks;
};

__device__ __forceinline__ h8v ldv(const _Float16* p_){ return *(const h8v*)p_; }

// Coherent flag poll: agent-scope RMW executes AT the LLC (proven R7).
__device__ __forceinline__ int poll(int* f){
  return __hip_atomic_fetch_add(f, 0, __ATOMIC_RELAXED, __HIP_MEMORY_SCOPE_AGENT);
}

// Ring publish: agent-scope atomic_exchange. The RMW executes at the LLC; the
// returned old value is kept live, so the vmcnt-ack == data committed at the
// coherence point (R2's producer construction — the one protocol element the
// failure matrix never implicated). This makes the step barrier's RELEASE
// FENCE unnecessary: by the time each wave drains vmcnt at barrier entry, its
// ring data is already AT the LLC.
__device__ __forceinline__ void ring_pub(u64* d, u64 v0, u64 v1){
  u64 o0 = __hip_atomic_exchange(d,   v0, __ATOMIC_RELAXED, __HIP_MEMORY_SCOPE_AGENT);
  u64 o1 = __hip_atomic_exchange(d+1, v1, __ATOMIC_RELAXED, __HIP_MEMORY_SCOPE_AGENT);
  asm volatile("" :: "v"(o0), "v"(o1));   // keep returns live: ack == LLC commit
}

// Full-grid fenced barrier — layer1 phase boundaries (bulk cached-store
// handoffs: needs both wbl2 release and inv acquire). R7-verbatim.
__device__ __forceinline__ void gbar(int* bar, int ep){
  __syncthreads();
  if (threadIdx.x == 0){
    __builtin_amdgcn_fence(__ATOMIC_RELEASE, "agent");   // L2 writeback to coherence point
    __hip_atomic_store(&bar[blockIdx.x*16], ep, __ATOMIC_RELAXED, __HIP_MEMORY_SCOPE_AGENT);
  }
  if (blockIdx.x == 0){
    for (int i = threadIdx.x; i < (int)gridDim.x; i += blockDim.x)
      while (poll(&bar[i*16]) < ep)
        __builtin_amdgcn_s_sleep(1);
    __syncthreads();
    if (threadIdx.x < 64)
      __hip_atomic_store(&bar[GOOFF + threadIdx.x*16], ep, __ATOMIC_RELAXED, __HIP_MEMORY_SCOPE_AGENT);
  } else {
    if (threadIdx.x == 0){
      while (poll(&bar[GOOFF + (blockIdx.x & 63)*16]) < ep)
        __builtin_amdgcn_s_sleep(1);
    }
  }
  __syncthreads();
  if (threadIdx.x < 64)
    __builtin_amdgcn_fence(__ATOMIC_ACQUIRE, "agent");   // single buffer_inv per WG
  __syncthreads();
}

// Per-direction step barrier: NO release fence (ring data already at LLC via
// exchange-publish; the __syncthreads drains every wave's vmcnt before the
// flag store). Consumer side is R7-proven: RMW poll + single-wave acquire inv.
__device__ __forceinline__ void abar(int* bar, int ep, int wgd, int n){
  __syncthreads();                       // all waves' exchanges acked -> data at LLC
  if (threadIdx.x == 0)
    __hip_atomic_store(&bar[wgd*16], ep, __ATOMIC_RELAXED, __HIP_MEMORY_SCOPE_AGENT);
  if (threadIdx.x < n){
    while (poll(&bar[threadIdx.x*16]) < ep)
      __builtin_amdgcn_s_sleep(1);
  }
  __syncthreads();
  if (threadIdx.x < 64)
    __builtin_amdgcn_fence(__ATOMIC_ACQUIRE, "agent");   // single buffer_inv per WG
  __syncthreads();
}

// ---- prep: permuted-row f16 weights. newrow = 4*u + gate (gate order i,f,g,o)
__global__ void prep_w(const float* __restrict__ src, _Float16* __restrict__ dst,
                       int Ks, int Kd){
  const long n = (long)2*G4*Kd;
  for (long i = blockIdx.x*(long)blockDim.x + threadIdx.x; i < n; i += (long)gridDim.x*blockDim.x){
    const int k  = (int)(i % Kd);
    const long rr = i / Kd;
    const int nr = (int)(rr % G4);
    const int d  = (int)(rr / G4);
    float v = 0.f;
    if (k < Ks){
      const int u = nr >> 2, g = nr & 3;
      v = src[((long)d*G4 + g*HID + u)*Ks + k];
    }
    dst[i] = (_Float16)v;
  }
}

__global__ void prep_xpad(const float* __restrict__ x, _Float16* __restrict__ dst){
  const long n = (long)LSEQ*NB*DKP;
  for (long i = blockIdx.x*(long)blockDim.x + threadIdx.x; i < n; i += (long)gridDim.x*blockDim.x){
    const int k = (int)(i % DKP);
    const long rr = i / DKP;
    const int bb = (int)(rr % NB);
    const int t  = (int)(rr / NB);
    float v = 0.f;
    if (k < DIN) v = x[((long)bb*LSEQ + t)*DIN + k];   // x is [B][L][Din]
    dst[i] = (_Float16)v;
  }
}

__global__ void prep_bias(const float* bi0, const float* bh0, const float* bi1, const float* bh1,
                          float* o0, float* o1, int* bar0, int* barG, int* barS){
  const int tid = blockIdx.x*blockDim.x + threadIdx.x;
  for (int i = tid; i < 2*G4; i += gridDim.x*blockDim.x){
    const int nr = i % G4, d = i / G4;
    const int u = nr >> 2, g = nr & 3;
    const int old = d*G4 + g*HID + u;
    o0[i] = bi0[old] + bh0[old];
    o1[i] = bi1[old] + bh1[old];
  }
  for (int i = tid; i < 2*RST; i += gridDim.x*blockDim.x){ bar0[i] = 0; barS[i] = 0; }
  for (int i = tid; i < BARN;  i += gridDim.x*blockDim.x)  barG[i] = 0;
}

// ---- layer 0: grid 100, 512 threads (8 waves), 50 WGs/dir. R7-verbatim compute;
// ring publish via exchange (LLC-committed), step barrier without release fence.
__global__ void __launch_bounds__(512, 1) layer0_kernel(P p){
  const int wg  = blockIdx.x;          // 0..99
  const int dir = wg / 50;
  const int wgd = wg % 50;
  const int wid = threadIdx.x >> 6;    // 0..7
  const int lane = threadIdx.x & 63;
  const int q = lane >> 4, c16 = lane & 15;
  const int wv = wgd*8 + wid;          // 0..399
  const int m  = wv >> 1;              // Mtile 0..199
  const int nt = wv & 1;
  const int b  = nt*16 + c16;
  const int ulocal = (wid >> 1)*4 + q; // 0..15: WG owns units 16*wgd..+16
  const int lw = (wid >> 1)*16 + c16;  // local weight row 0..63
  const int rowb = m*16 + q*4;
  const int rep = wgd & (NREP-1);
  float cst = 0.f;
  __shared__ _Float16 hT[2][16][32];
  __shared__ _Float16 wlds[64*WP];     // 103.4 KB: this WG's 64 W_hh gate rows

  // stage W_hh rows [dir*G4 + wgd*64 .. +64) into LDS once
  {
    const long base_row = (long)dir*G4 + wgd*64;
    for (int idx = threadIdx.x; idx < 6400; idx += 512){
      const int lr = idx / 100, c = idx % 100;
      *(h8v*)(wlds + lr*WP + c*8) = ldv(p.w0hh + (base_row + lr)*HID + c*8);
    }
  }
  __syncthreads();

  const long wih_row = ((long)dir*G4 + m*16 + c16)*DKP;
  int* bar = p.bar0 + dir*RST;
  const f4v bias = *(const f4v*)(p.bias0 + dir*G4 + rowb);

  // prologue: x-GEMM for s=0
  f4v xacc = {0.f,0.f,0.f,0.f};
  {
    const int t0 = dir ? (LSEQ-1) : 0;
    const long xb = ((long)t0*NB + b)*DKP;
    #pragma unroll
    for (int kk = 0; kk < 2; ++kk){
      const int ko = kk*32 + q*8;
      xacc = __builtin_amdgcn_mfma_f32_16x16x32_f16(
               ldv(p.w0ih + wih_row + ko), ldv(p.xp + xb + ko), xacc, 0, 0, 0);
    }
  }

  for (int s = 0; s < LSEQ; ++s){
    const int t  = dir ? (LSEQ-1-s) : s;
    f4v acc = xacc;                    // x contribution, same FP order as R3
    f4v accl = {0.f,0.f,0.f,0.f};
    if (s > 0){
      const long hb = (((long)((s-1)&1)*NREP + rep)*NB + b)*H2 + dir*HID;
      const _Float16* rh = p.hr0h + hb;
      const _Float16* rl = p.hr0l + hb;
      const _Float16* wl = wlds + lw*WP;
      #pragma unroll
      for (int kk = 0; kk < 25; ++kk){
        const int ko = kk*32 + q*8;
        const h8v aw = *(const h8v*)(wl + ko);
        acc  = __builtin_amdgcn_mfma_f32_16x16x32_f16(aw, ldv(rh + ko), acc,  0, 0, 0);
        accl = __builtin_amdgcn_mfma_f32_16x16x32_f16(aw, ldv(rl + ko), accl, 0, 0, 0);
      }
    }
    const float gi = acc[0] + accl[0]*ISC + bias[0];
    const float gf = acc[1] + accl[1]*ISC + bias[1];
    const float gg = acc[2] + accl[2]*ISC + bias[2];
    const float go = acc[3] + accl[3]*ISC + bias[3];
    const float si = 1.f/(1.f + __expf(-gi));
    const float sf = 1.f/(1.f + __expf(-gf));
    const float so = 1.f/(1.f + __expf(-go));
    cst = sf*cst + si*tanhf(gg);
    const float h = so*tanhf(cst);
    const _Float16 hi = (_Float16)h;
    hT[0][ulocal][b] = hi;
    hT[1][ulocal][b] = (_Float16)((h - (float)hi)*SCAL);
    __syncthreads();
    {
      // publish: each of 512 threads exchanges one 16B replica share into the
      // ring (LLC-committed by ack); h0 stays plain-cached (kernel-end flush).
      const int tid = threadIdx.x;
      const int r = tid >> 7;
      const int rem = tid & 127;
      const int part = rem >> 6;
      const int ub = (rem >> 5) & 1;
      const int bb = rem & 31;
      h8v v;
      #pragma unroll
      for (int uu = 0; uu < 8; ++uu) v[uu] = hT[part][ub*8 + uu][bb];
      if (r == 0 && part == 0)
        *(h8v*)(p.h0 + (long)t*NB*H2 + (long)bb*H2 + dir*HID + wgd*16 + ub*8) = v;
      union { h8v v; u64 u[2]; } pv; pv.v = v;
      u64* d = (u64*)((part ? p.hr0l : p.hr0h)
              + (((long)(s&1)*NREP + r)*NB + bb)*H2 + dir*HID + wgd*16 + ub*8);
      ring_pub(d, pv.u[0], pv.u[1]);
    }
    // prefetch next step's x-GEMM before the barrier
    f4v xn = {0.f,0.f,0.f,0.f};
    if (s + 1 < LSEQ){
      const int t2 = dir ? (LSEQ-2-s) : (s+1);
      const long xb2 = ((long)t2*NB + b)*DKP;
      #pragma unroll
      for (int kk = 0; kk < 2; ++kk){
        const int ko = kk*32 + q*8;
        xn = __builtin_amdgcn_mfma_f32_16x16x32_f16(
               ldv(p.w0ih + wih_row + ko), ldv(p.xp + xb2 + ko), xn, 0, 0, 0);
      }
    }
    xacc = xn;
    abar(bar, s+1, wgd, 50);
  }
}

// ---- layer 1: grid 256, 4 waves. R7-verbatim; exchange-publish + fence-light abar.
__global__ void __launch_bounds__(256, 1) layer1_kernel(P p){
  const int wg  = blockIdx.x;
  const int dir = wg >> 7;
  const int wgd = wg & 127;
  const int wid = threadIdx.x >> 6;
  const int lane = threadIdx.x & 63;
  const int q = lane >> 4, c16 = lane & 15;
  const bool act = (wgd < 100);
  const int wv = wgd*4 + wid;
  const int m  = wv >> 1;
  const int nt = wv & 1;
  const int b  = nt*16 + c16;
  const int ulocal = (wid >> 1)*4 + q;
  const int lw = (wid >> 1)*16 + c16;
  const int rowb = m*16 + q*4;
  const int rep = wgd & (NREP-1);
  float cst = 0.f;
  __shared__ _Float16 hT[2][8][32];
  __shared__ _Float16 wlds[32*WP];
  int* barS = p.barS + dir*RST;
  const int Tc = p.Tc;
  const int SL = Tc + 1;
  const int ntN = Tc >> 2;
  const int tilesPerDir = 25*ntN;
  const int TILES = 2*tilesPerDir;
  int ep = 0;

  if (act){
    const long base_row = (long)dir*G4 + wgd*32;
    for (int idx = threadIdx.x; idx < 3200; idx += 256){
      const int lr = idx / 100, c = idx % 100;
      *(h8v*)(wlds + lr*WP + c*8) = ldv(p.w1hh + (base_row + lr)*HID + c*8);
    }
  }
  __syncthreads();

  for (int ci = 0; ci < p.nchunks; ++ci){
    // ---------- GEMM phase ----------
    for (int tile = blockIdx.x; tile < TILES; tile += gridDim.x){
      const int d   = tile / tilesPerDir;
      const int rem = tile % tilesPerDir;
      const int mi  = rem / ntN;
      const int ni  = rem % ntN;
      const int M0  = mi*128 + (wid >> 1)*64;
      const int N0  = ni*128 + (wid & 1)*64;
      f4v acc[4][4];
      #pragma unroll
      for (int ai=0; ai<4; ++ai)
        #pragma unroll
        for (int bi=0; bi<4; ++bi) acc[ai][bi] = (f4v){0,0,0,0};
      long hrow[4], arow[4];
      #pragma unroll
      for (int bi=0; bi<4; ++bi){
        const int n0 = N0 + bi*16;
        const int j  = n0 >> 5;
        const int bb = (n0 & 31) + c16;
        const int t  = d ? (LSEQ-1 - (ci*Tc + j)) : (ci*Tc + j);
        hrow[bi] = ((long)t*NB + bb)*H2;
      }
      #pragma unroll
      for (int ai=0; ai<4; ++ai) arow[ai] = ((long)d*G4 + M0 + ai*16 + c16)*H2;

      for (int kk = 0; kk < 50; ++kk){
        const int ko = kk*32 + q*8;
        h8v Ah[4], Bh[4];
        #pragma unroll
        for (int ai=0; ai<4; ++ai) Ah[ai] = ldv(p.w1ih + arow[ai] + ko);
        #pragma unroll
        for (int bi=0; bi<4; ++bi) Bh[bi] = ldv(p.h0 + hrow[bi] + ko);
        #pragma unroll
        for (int ai=0; ai<4; ++ai)
          #pragma unroll
          for (int bi=0; bi<4; ++bi)
            acc[ai][bi] = __builtin_amdgcn_mfma_f32_16x16x32_f16(Ah[ai], Bh[bi], acc[ai][bi], 0, 0, 0);
      }
      #pragma unroll
      for (int ai=0; ai<4; ++ai){
        const int row0 = M0 + ai*16 + q*4;
        const f4v bv = *(const f4v*)(p.bias1 + d*G4 + row0);
        #pragma unroll
        for (int bi=0; bi<4; ++bi){
          const int n0 = N0 + bi*16;
          const int j  = n0 >> 5;
          const int bb = (n0 & 31) + c16;
          f4v val = acc[ai][bi] + bv;
          *(f4v*)(p.gx1 + ((((long)d*Tc + j)*800 + (row0 >> 2))*NB + bb)*4) = val;
        }
      }
    }
    gbar(p.barG, ++ep);
    // ---------- recurrent steps (fence-light abar, active WGs) ----------
    if (act){
      f4v accNext = *(const f4v*)(p.gx1 + ((((long)dir*Tc + 0)*800 + (rowb >> 2))*NB + b)*4);
      for (int sl = 0; sl < Tc; ++sl){
        const int s  = ci*Tc + sl;
        f4v acc = accNext;
        f4v accl = {0.f,0.f,0.f,0.f};
        if (s > 0){
          const long hb = (((long)((s-1)&1)*NREP + rep)*NB + b)*H2 + dir*HID;
          const _Float16* rh = p.r1h + hb;
          const _Float16* rl = p.r1l + hb;
          const _Float16* wl = wlds + lw*WP;
          #pragma unroll
          for (int kk = 0; kk < 25; ++kk){
            const int ko = kk*32 + q*8;
            const h8v aw = *(const h8v*)(wl + ko);
            acc  = __builtin_amdgcn_mfma_f32_16x16x32_f16(aw, ldv(rh + ko), acc,  0, 0, 0);
            accl = __builtin_amdgcn_mfma_f32_16x16x32_f16(aw, ldv(rl + ko), accl, 0, 0, 0);
          }
        }
        const float si = 1.f/(1.f + __expf(-(acc[0] + accl[0]*ISC)));
        const float sf = 1.f/(1.f + __expf(-(acc[1] + accl[1]*ISC)));
        const float so = 1.f/(1.f + __expf(-(acc[3] + accl[3]*ISC)));
        cst = sf*cst + si*tanhf(acc[2] + accl[2]*ISC);
        const float h = so*tanhf(cst);
        const _Float16 hi = (_Float16)h;
        hT[0][ulocal][b] = hi;
        hT[1][ulocal][b] = (_Float16)((h - (float)hi)*SCAL);
        __syncthreads();
        {
          const int tid = threadIdx.x;
          const int r = tid >> 6, part = (tid >> 5) & 1, bb = tid & 31;
          const int slot = s % SL;
          h8v v;
          #pragma unroll
          for (int uu = 0; uu < 8; ++uu) v[uu] = hT[part][uu][bb];
          if (r == 0)
            *(h8v*)((part ? p.h1wl : p.h1wh) + ((long)slot*NB + bb)*H2 + dir*HID + wgd*8) = v;
          union { h8v v; u64 u[2]; } pv; pv.v = v;
          u64* d = (u64*)((part ? p.r1l : p.r1h)
                  + (((long)(s&1)*NREP + r)*NB + bb)*H2 + dir*HID + wgd*8);
          ring_pub(d, pv.u[0], pv.u[1]);
        }
        // prefetch next gx1 (immutable within chunk) before the barrier
        if (sl + 1 < Tc)
          accNext = *(const f4v*)(p.gx1 + ((((long)dir*Tc + sl+1)*800 + (rowb >> 2))*NB + b)*4);
        abar(barS, s+1, wgd, 100);
      }
    }
    gbar(p.barG, ++ep);
    // ---------- logits phase ----------
    for (int pi = blockIdx.x; pi < 2*Tc; pi += gridDim.x){
      const int sl = pi >> 1, d = pi & 1;
      const int s  = ci*Tc + sl;
      const int t  = d ? (LSEQ-1-s) : s;
      const int slot = s % SL;
      const int bb = threadIdx.x & 31;
      const int k0 = threadIdx.x >> 5;
      const _Float16* hp  = p.h1wh + ((long)slot*NB + bb)*H2 + d*HID;
      const _Float16* hp2 = p.h1wl + ((long)slot*NB + bb)*H2 + d*HID;
      float* lp = (d ? p.logits1 : p.logits0) + ((long)t*NB + bb)*20;
      for (int k = k0; k < 20; k += 8){
        const float* wrow = p.w_lin + (long)k*H2 + d*HID;
        float acc2 = 0.f;
        for (int u = 0; u < HID; u += 8){
          h8v hv = ldv(hp + u);
          h8v lv = ldv(hp2 + u);
          #pragma unroll
          for (int j2 = 0; j2 < 8; ++j2)
            acc2 += ((float)hv[j2] + (float)lv[j2]*ISC) * wrow[u + j2];
        }
        lp[k] = acc2;
      }
    }
    gbar(p.barG, ++ep);
  }
}

// ---- head: logits -> softmax over BATCH axis -> angles -> dvec (reshape-scramble aware)
__global__ void head_kernel(P p){
  const int l = blockIdx.x;
  const int tid = threadIdx.x;
  __shared__ float lg[NB][20];
  __shared__ float sA[20][3], cA2[20][3];
  if (tid < 60){
    const float a = p.alphabet[tid];
    sA[tid/3][tid%3]  = sinf(a);
    cA2[tid/3][tid%3] = cosf(a);
  }
  for (int i = tid; i < NB*20; i += blockDim.x){
    const int bb = i / 20, k = i % 20;
    lg[bb][k] = p.logits0[((long)l*NB + bb)*20 + k] +
                p.logits1[((long)l*NB + bb)*20 + k] + p.b_lin[k];
  }
  __syncthreads();
  if (tid < 20){
    float mx = -1e30f;
    for (int bb=0; bb<NB; ++bb) mx = fmaxf(mx, lg[bb][tid]);
    float sum = 0.f;
    for (int bb=0; bb<NB; ++bb) sum += expf(lg[bb][tid] - mx);
    const float inv = 1.f/sum;
    for (int bb=0; bb<NB; ++bb) lg[bb][tid] = expf(lg[bb][tid] - mx)*inv;
  }
  __syncthreads();
  if (tid < 96){
    const int bb = tid/3, dd = tid%3;     // angle source (ang[l][bb][dd])
    const int pp = tid >> 5;              // scan row within step-triple
    const int j  = tid & 31;              // NeRF lane (column of phis)
    float ss = 0.f, cc = 0.f;
    #pragma unroll
    for (int k=0; k<20; ++k){ ss += lg[bb][k]*sA[k][dd]; cc += lg[bb][k]*cA2[k][dd]; }
    const float phi = atan2f(ss, cc);
    const float BL[3] = {145.801f, 152.326f, 132.868f};
    const float BA[3] = {2.124f, 1.941f, 2.028f};
    const float r = BL[pp], th = BA[pp];
    float* dv = p.dvec + ((long)(l*3 + pp)*NB + j)*4;
    dv[0] = -r*cosf(th);
    dv[1] = r*sinf(th)*cosf(phi);
    dv[2] = r*sinf(th)*sinf(phi);
  }
}

// ---- NeRF extension: strictly sequential, 1 lane per scan column.
__global__ void nerf_kernel(P p){
  const int bb = threadIdx.x;
  if (bb >= NB) return;
  float ax=0.f,ay=0.f,az=0.f, bx=100.f,by=0.f,bz=0.f, cx=200.f,cy=100.f,cz=0.f;
  for (int i = 0; i < 3*LSEQ; ++i){
    const float* dv = p.dvec + ((long)i*NB + bb)*4;
    const float d0=dv[0], d1=dv[1], d2=dv[2];
    float ux=cx-bx, uy=cy-by, uz=cz-bz;
    float inv = 1.f/(sqrtf(ux*ux+uy*uy+uz*uz)+1e-12f);
    ux*=inv; uy*=inv; uz*=inv;
    const float px=bx-ax, py=by-ay, pz=bz-az;
    float nx=py*uz-pz*uy, ny=pz*ux-px*uz, nz=px*uy-py*ux;
    inv = 1.f/(sqrtf(nx*nx+ny*ny+nz*nz)+1e-12f);
    nx*=inv; ny*=inv; nz*=inv;
    const float mx=ny*uz-nz*uy, my=nz*ux-nx*uz, mz=nx*uy-ny*ux;
    const float Dx = cx + d0*ux + d1*mx + d2*nx;
    const float Dy = cy + d0*uy + d1*my + d2*ny;
    const float Dz = cz + d0*uz + d1*mz + d2*nz;
    float* o = p.out + ((long)i*NB + bb)*3;
    o[0]=Dx; o[1]=Dy; o[2]=Dz;
    ax=bx; ay=by; az=bz;
    bx=cx; by=cy; bz=cz;
    cx=Dx; cy=Dy; cz=Dz;
  }
}

extern "C" void kernel_launch(void* const* d_in, const int* in_sizes, int n_in,
                              void* d_out, int out_size, void* d_ws, size_t ws_size,
                              hipStream_t stream){
  P p{};
  p.x      = (const float*)d_in[0];
  p.w_ih0  = (const float*)d_in[1];
  p.w_hh0  = (const float*)d_in[2];
  p.b_ih0  = (const float*)d_in[3];
  p.b_hh0  = (const float*)d_in[4];
  p.w_ih1  = (const float*)d_in[5];
  p.w_hh1  = (const float*)d_in[6];
  p.b_ih1  = (const float*)d_in[7];
  p.b_hh1  = (const float*)d_in[8];
  p.w_lin  = (const float*)d_in[9];
  p.b_lin  = (const float*)d_in[10];
  p.alphabet = (const float*)d_in[11];
  p.out    = (float*)d_out;

  char* base = (char*)d_ws;
  size_t off = 0;
  auto alloc = [&](size_t bytes)->void*{
    void* r = base + off;
    off = (off + bytes + 255) & ~(size_t)255;
    return r;
  };
  p.h0      = (_Float16*)alloc((size_t)LSEQ*NB*H2*2);        // 71.68 MB
  p.hr0h    = (_Float16*)alloc((size_t)2*NREP*NB*H2*2);      // 0.82 MB
  p.hr0l    = (_Float16*)alloc((size_t)2*NREP*NB*H2*2);
  p.r1h     = (_Float16*)alloc((size_t)2*NREP*NB*H2*2);
  p.r1l     = (_Float16*)alloc((size_t)2*NREP*NB*H2*2);
  p.w0hh    = (_Float16*)alloc((size_t)2*G4*HID*2);          // 10.24 MB
  p.w1hh    = (_Float16*)alloc((size_t)2*G4*HID*2);          // 10.24 MB
  p.w1ih    = (_Float16*)alloc((size_t)2*G4*H2*2);           // 20.48 MB
  p.w0ih    = (_Float16*)alloc((size_t)2*G4*DKP*2);
  p.xp      = (_Float16*)alloc((size_t)LSEQ*NB*DKP*2);
  p.bias0   = (float*)alloc((size_t)2*G4*4);
  p.bias1   = (float*)alloc((size_t)2*G4*4);
  p.logits0 = (float*)alloc((size_t)LSEQ*NB*20*4);
  p.logits1 = (float*)alloc((size_t)LSEQ*NB*20*4);
  p.dvec    = (float*)alloc((size_t)3*LSEQ*NB*4*4);
  p.bar0    = (int*)alloc((size_t)2*RST*4);
  p.barG    = (int*)alloc((size_t)BARN*4);
  p.barS    = (int*)alloc((size_t)2*RST*4);

  const int cands[5] = {140, 100, 28, 20, 4};   // must divide 700 and be %4==0
  int Tc = 4;
  for (int i = 0; i < 5; ++i){
    const size_t need = off
      + (size_t)2*cands[i]*800*NB*4*4 + 256
      + (size_t)2*(cands[i]+1)*NB*H2*2 + 512;
    if (need <= ws_size){ Tc = cands[i]; break; }
  }
  p.gx1  = (float*)alloc((size_t)2*Tc*800*NB*4*4);
  p.h1wh = (_Float16*)alloc((size_t)(Tc+1)*NB*H2*2);
  p.h1wl = (_Float16*)alloc((size_t)(Tc+1)*NB*H2*2);
  p.Tc = Tc;
  p.nchunks = LSEQ / Tc;

  hipLaunchKernelGGL(prep_w, dim3(1024), dim3(256), 0, stream, p.w_hh0, p.w0hh, HID, HID);
  hipLaunchKernelGGL(prep_w, dim3(1024), dim3(256), 0, stream, p.w_hh1, p.w1hh, HID, HID);
  hipLaunchKernelGGL(prep_w, dim3(2048), dim3(256), 0, stream, p.w_ih1, p.w1ih, H2, H2);
  hipLaunchKernelGGL(prep_w, dim3(256),  dim3(256), 0, stream, p.w_ih0, p.w0ih, DIN, DKP);
  hipLaunchKernelGGL(prep_xpad, dim3(512), dim3(256), 0, stream, p.x, p.xp);
  hipLaunchKernelGGL(prep_bias, dim3(32), dim3(256), 0, stream,
                     p.b_ih0, p.b_hh0, p.b_ih1, p.b_hh1, p.bias0, p.bias1,
                     p.bar0, p.barG, p.barS);

  void* args[] = { &p };
  hipLaunchCooperativeKernel((void*)layer0_kernel, dim3(100), dim3(512), args, 0, stream);
  hipLaunchCooperativeKernel((void*)layer1_kernel, dim3(256), dim3(256), args, 0, stream);
  hipLaunchKernelGGL(head_kernel, dim3(LSEQ), dim3(256), 0, stream, p);
  hipLaunchKernelGGL(nerf_kernel, dim3(1), dim3(64), 0, stream, p);
}

// Round 9
// 19730.919 us; speedup vs baseline: 1.7918x; 1.1453x over previous
//
#include <hip/hip_runtime.h>

#define LSEQ 700
#define NB   32
#define DIN  41
#define HID  800
#define G4   3200   // 4*H gate rows
#define H2   1600   // 2*H
#define DKP  64     // Din padded to MFMA K granularity
#define NREP 1      // R9: replicas removed — post-R7 the per-XCD L2 absorbs intra-XCD
                    // sharing; replication multiplied LLC pull 4x and inv-refetch exposure
#define WP   808    // LDS weight row stride (f16): 1616B -> 2-way bank alias (free)

#define SCAL 2048.f
#define ISC  (1.f/2048.f)

// full-grid gbar region: 256 arrive flags (64B stride) + 64 go words (64B stride)
#define GOOFF (256*16)
#define BARN  (256*16 + 64*16)
// per-direction step-barrier region: 128 arrive flags (64B stride)
#define RST   (192*16)

typedef _Float16 h8v __attribute__((ext_vector_type(8)));  // 8 f16 = 4 VGPRs (MFMA A/B frag)
typedef float    f4v __attribute__((ext_vector_type(4)));
typedef unsigned long long u64;

struct P {
  const float *x, *w_ih0, *w_hh0, *b_ih0, *b_hh0;
  const float *w_ih1, *w_hh1, *b_ih1, *b_hh1;
  const float *w_lin, *b_lin, *alphabet;
  _Float16 *h0;                    // [t][b][dir*800+u] f16 hi — full history (layer1 GEMM input)
  _Float16 *hr0h, *hr0l;           // layer0 depth-2 ring [slot][b][dir*800+u]
  _Float16 *r1h,  *r1l;            // layer1 depth-2 ring
  _Float16 *h1wh, *h1wl;           // layer1 SL ring [slot][b][dir*800+u] (logits reads after gbar)
  _Float16 *w0hh, *w1hh;           // [dir][permrow 4u+g][800]
  _Float16 *w1ih;                  // [dir][permrow][1600]
  _Float16 *w0ih;                  // [dir][permrow][64]
  _Float16 *xp;                    // [t][b][64]
  float *bias0, *bias1;            // [dir][permrow]
  float *logits0, *logits1;        // [t][b][20]
  float *dvec;                     // [3L][j][4]
  float *gx1;                      // [d][sl][unit][b][4] f32
  float *out;
  int *bar0;                       // layer0 per-dir step-barrier regions [2][RST]
  int *barG;                       // layer1 full-grid gbar (phase boundaries)
  int *barS;                       // layer1 per-dir step-barrier regions [2][RST]
  int Tc, nchunks;
};

__device__ __forceinline__ h8v ldv(const _Float16* p_){ return *(const h8v*)p_; }

// Coherent flag poll: agent-scope RMW executes AT the LLC (proven R7).
__device__ __forceinline__ int poll(int* f){
  return __hip_atomic_fetch_add(f, 0, __ATOMIC_RELAXED, __HIP_MEMORY_SCOPE_AGENT);
}

// Ring publish: agent-scope atomic_exchange; returned old value kept live so
// vmcnt-ack == data committed at the LLC coherence point (proven R8: removed
// the step barrier's release fence).
__device__ __forceinline__ void ring_pub(u64* d, u64 v0, u64 v1){
  u64 o0 = __hip_atomic_exchange(d,   v0, __ATOMIC_RELAXED, __HIP_MEMORY_SCOPE_AGENT);
  u64 o1 = __hip_atomic_exchange(d+1, v1, __ATOMIC_RELAXED, __HIP_MEMORY_SCOPE_AGENT);
  asm volatile("" :: "v"(o0), "v"(o1));   // keep returns live: ack == LLC commit
}

// Full-grid fenced barrier — layer1 phase boundaries (bulk cached-store
// handoffs: needs both wbl2 release and inv acquire). R7-verbatim.
__device__ __forceinline__ void gbar(int* bar, int ep){
  __syncthreads();
  if (threadIdx.x == 0){
    __builtin_amdgcn_fence(__ATOMIC_RELEASE, "agent");   // L2 writeback to coherence point
    __hip_atomic_store(&bar[blockIdx.x*16], ep, __ATOMIC_RELAXED, __HIP_MEMORY_SCOPE_AGENT);
  }
  if (blockIdx.x == 0){
    for (int i = threadIdx.x; i < (int)gridDim.x; i += blockDim.x)
      while (poll(&bar[i*16]) < ep)
        __builtin_amdgcn_s_sleep(1);
    __syncthreads();
    if (threadIdx.x < 64)
      __hip_atomic_store(&bar[GOOFF + threadIdx.x*16], ep, __ATOMIC_RELAXED, __HIP_MEMORY_SCOPE_AGENT);
  } else {
    if (threadIdx.x == 0){
      while (poll(&bar[GOOFF + (blockIdx.x & 63)*16]) < ep)
        __builtin_amdgcn_s_sleep(1);
    }
  }
  __syncthreads();
  if (threadIdx.x < 64)
    __builtin_amdgcn_fence(__ATOMIC_ACQUIRE, "agent");   // single buffer_inv per WG
  __syncthreads();
}

// Per-direction step barrier: no release fence (exchange-publish already
// LLC-committed); RMW poll; single-wave acquire inv. R8-verbatim.
__device__ __forceinline__ void abar(int* bar, int ep, int wgd, int n){
  __syncthreads();                       // all waves' exchanges acked -> data at LLC
  if (threadIdx.x == 0)
    __hip_atomic_store(&bar[wgd*16], ep, __ATOMIC_RELAXED, __HIP_MEMORY_SCOPE_AGENT);
  if (threadIdx.x < n){
    while (poll(&bar[threadIdx.x*16]) < ep)
      __builtin_amdgcn_s_sleep(1);
  }
  __syncthreads();
  if (threadIdx.x < 64)
    __builtin_amdgcn_fence(__ATOMIC_ACQUIRE, "agent");   // single buffer_inv per WG
  __syncthreads();
}

// ---- prep: permuted-row f16 weights. newrow = 4*u + gate (gate order i,f,g,o)
__global__ void prep_w(const float* __restrict__ src, _Float16* __restrict__ dst,
                       int Ks, int Kd){
  const long n = (long)2*G4*Kd;
  for (long i = blockIdx.x*(long)blockDim.x + threadIdx.x; i < n; i += (long)gridDim.x*blockDim.x){
    const int k  = (int)(i % Kd);
    const long rr = i / Kd;
    const int nr = (int)(rr % G4);
    const int d  = (int)(rr / G4);
    float v = 0.f;
    if (k < Ks){
      const int u = nr >> 2, g = nr & 3;
      v = src[((long)d*G4 + g*HID + u)*Ks + k];
    }
    dst[i] = (_Float16)v;
  }
}

__global__ void prep_xpad(const float* __restrict__ x, _Float16* __restrict__ dst){
  const long n = (long)LSEQ*NB*DKP;
  for (long i = blockIdx.x*(long)blockDim.x + threadIdx.x; i < n; i += (long)gridDim.x*blockDim.x){
    const int k = (int)(i % DKP);
    const long rr = i / DKP;
    const int bb = (int)(rr % NB);
    const int t  = (int)(rr / NB);
    float v = 0.f;
    if (k < DIN) v = x[((long)bb*LSEQ + t)*DIN + k];   // x is [B][L][Din]
    dst[i] = (_Float16)v;
  }
}

__global__ void prep_bias(const float* bi0, const float* bh0, const float* bi1, const float* bh1,
                          float* o0, float* o1, int* bar0, int* barG, int* barS){
  const int tid = blockIdx.x*blockDim.x + threadIdx.x;
  for (int i = tid; i < 2*G4; i += gridDim.x*blockDim.x){
    const int nr = i % G4, d = i / G4;
    const int u = nr >> 2, g = nr & 3;
    const int old = d*G4 + g*HID + u;
    o0[i] = bi0[old] + bh0[old];
    o1[i] = bi1[old] + bh1[old];
  }
  for (int i = tid; i < 2*RST; i += gridDim.x*blockDim.x){ bar0[i] = 0; barS[i] = 0; }
  for (int i = tid; i < BARN;  i += gridDim.x*blockDim.x)  barG[i] = 0;
}

// ---- layer 0: grid 100, 512 threads (8 waves), 50 WGs/dir. R8-verbatim compute;
// single ring copy (no replicas): all WGs in an XCD share the same ring lines
// -> L2 dedups intra-XCD reads, 4x less LLC pull per step.
__global__ void __launch_bounds__(512, 1) layer0_kernel(P p){
  const int wg  = blockIdx.x;          // 0..99
  const int dir = wg / 50;
  const int wgd = wg % 50;
  const int wid = threadIdx.x >> 6;    // 0..7
  const int lane = threadIdx.x & 63;
  const int q = lane >> 4, c16 = lane & 15;
  const int wv = wgd*8 + wid;          // 0..399
  const int m  = wv >> 1;              // Mtile 0..199
  const int nt = wv & 1;
  const int b  = nt*16 + c16;
  const int ulocal = (wid >> 1)*4 + q; // 0..15: WG owns units 16*wgd..+16
  const int lw = (wid >> 1)*16 + c16;  // local weight row 0..63
  const int rowb = m*16 + q*4;
  float cst = 0.f;
  __shared__ _Float16 hT[2][16][32];
  __shared__ _Float16 wlds[64*WP];     // 103.4 KB: this WG's 64 W_hh gate rows

  // stage W_hh rows [dir*G4 + wgd*64 .. +64) into LDS once
  {
    const long base_row = (long)dir*G4 + wgd*64;
    for (int idx = threadIdx.x; idx < 6400; idx += 512){
      const int lr = idx / 100, c = idx % 100;
      *(h8v*)(wlds + lr*WP + c*8) = ldv(p.w0hh + (base_row + lr)*HID + c*8);
    }
  }
  __syncthreads();

  const long wih_row = ((long)dir*G4 + m*16 + c16)*DKP;
  int* bar = p.bar0 + dir*RST;
  const f4v bias = *(const f4v*)(p.bias0 + dir*G4 + rowb);

  // prologue: x-GEMM for s=0
  f4v xacc = {0.f,0.f,0.f,0.f};
  {
    const int t0 = dir ? (LSEQ-1) : 0;
    const long xb = ((long)t0*NB + b)*DKP;
    #pragma unroll
    for (int kk = 0; kk < 2; ++kk){
      const int ko = kk*32 + q*8;
      xacc = __builtin_amdgcn_mfma_f32_16x16x32_f16(
               ldv(p.w0ih + wih_row + ko), ldv(p.xp + xb + ko), xacc, 0, 0, 0);
    }
  }

  for (int s = 0; s < LSEQ; ++s){
    const int t  = dir ? (LSEQ-1-s) : s;
    f4v acc = xacc;                    // x contribution, same FP order as R3
    f4v accl = {0.f,0.f,0.f,0.f};
    if (s > 0){
      const long hb = ((long)((s-1)&1)*NB + b)*H2 + dir*HID;
      const _Float16* rh = p.hr0h + hb;
      const _Float16* rl = p.hr0l + hb;
      const _Float16* wl = wlds + lw*WP;
      #pragma unroll
      for (int kk = 0; kk < 25; ++kk){
        const int ko = kk*32 + q*8;
        const h8v aw = *(const h8v*)(wl + ko);
        acc  = __builtin_amdgcn_mfma_f32_16x16x32_f16(aw, ldv(rh + ko), acc,  0, 0, 0);
        accl = __builtin_amdgcn_mfma_f32_16x16x32_f16(aw, ldv(rl + ko), accl, 0, 0, 0);
      }
    }
    const float gi = acc[0] + accl[0]*ISC + bias[0];
    const float gf = acc[1] + accl[1]*ISC + bias[1];
    const float gg = acc[2] + accl[2]*ISC + bias[2];
    const float go = acc[3] + accl[3]*ISC + bias[3];
    const float si = 1.f/(1.f + __expf(-gi));
    const float sf = 1.f/(1.f + __expf(-gf));
    const float so = 1.f/(1.f + __expf(-go));
    cst = sf*cst + si*tanhf(gg);
    const float h = so*tanhf(cst);
    const _Float16 hi = (_Float16)h;
    hT[0][ulocal][b] = hi;
    hT[1][ulocal][b] = (_Float16)((h - (float)hi)*SCAL);
    __syncthreads();
    {
      // publish: 128 threads each exchange one 16B share into the single ring
      // copy (LLC-committed by ack); h0 stays plain-cached (kernel-end flush).
      const int tid = threadIdx.x;
      if (tid < 128){
        const int part = tid >> 6;     // hi/lo
        const int ub = (tid >> 5) & 1; // unit block (8 units)
        const int bb = tid & 31;       // batch
        h8v v;
        #pragma unroll
        for (int uu = 0; uu < 8; ++uu) v[uu] = hT[part][ub*8 + uu][bb];
        if (part == 0)
          *(h8v*)(p.h0 + (long)t*NB*H2 + (long)bb*H2 + dir*HID + wgd*16 + ub*8) = v;
        union { h8v v; u64 u[2]; } pv; pv.v = v;
        u64* d = (u64*)((part ? p.hr0l : p.hr0h)
                + ((long)(s&1)*NB + bb)*H2 + dir*HID + wgd*16 + ub*8);
        ring_pub(d, pv.u[0], pv.u[1]);
      }
    }
    // prefetch next step's x-GEMM before the barrier
    f4v xn = {0.f,0.f,0.f,0.f};
    if (s + 1 < LSEQ){
      const int t2 = dir ? (LSEQ-2-s) : (s+1);
      const long xb2 = ((long)t2*NB + b)*DKP;
      #pragma unroll
      for (int kk = 0; kk < 2; ++kk){
        const int ko = kk*32 + q*8;
        xn = __builtin_amdgcn_mfma_f32_16x16x32_f16(
               ldv(p.w0ih + wih_row + ko), ldv(p.xp + xb2 + ko), xn, 0, 0, 0);
      }
    }
    xacc = xn;
    abar(bar, s+1, wgd, 50);
  }
}

// ---- layer 1: grid 256, 4 waves. R8-verbatim; single ring copy.
__global__ void __launch_bounds__(256, 1) layer1_kernel(P p){
  const int wg  = blockIdx.x;
  const int dir = wg >> 7;
  const int wgd = wg & 127;
  const int wid = threadIdx.x >> 6;
  const int lane = threadIdx.x & 63;
  const int q = lane >> 4, c16 = lane & 15;
  const bool act = (wgd < 100);
  const int wv = wgd*4 + wid;
  const int m  = wv >> 1;
  const int nt = wv & 1;
  const int b  = nt*16 + c16;
  const int ulocal = (wid >> 1)*4 + q;
  const int lw = (wid >> 1)*16 + c16;
  const int rowb = m*16 + q*4;
  float cst = 0.f;
  __shared__ _Float16 hT[2][8][32];
  __shared__ _Float16 wlds[32*WP];
  int* barS = p.barS + dir*RST;
  const int Tc = p.Tc;
  const int SL = Tc + 1;
  const int ntN = Tc >> 2;
  const int tilesPerDir = 25*ntN;
  const int TILES = 2*tilesPerDir;
  int ep = 0;

  if (act){
    const long base_row = (long)dir*G4 + wgd*32;
    for (int idx = threadIdx.x; idx < 3200; idx += 256){
      const int lr = idx / 100, c = idx % 100;
      *(h8v*)(wlds + lr*WP + c*8) = ldv(p.w1hh + (base_row + lr)*HID + c*8);
    }
  }
  __syncthreads();

  for (int ci = 0; ci < p.nchunks; ++ci){
    // ---------- GEMM phase ----------
    for (int tile = blockIdx.x; tile < TILES; tile += gridDim.x){
      const int d   = tile / tilesPerDir;
      const int rem = tile % tilesPerDir;
      const int mi  = rem / ntN;
      const int ni  = rem % ntN;
      const int M0  = mi*128 + (wid >> 1)*64;
      const int N0  = ni*128 + (wid & 1)*64;
      f4v acc[4][4];
      #pragma unroll
      for (int ai=0; ai<4; ++ai)
        #pragma unroll
        for (int bi=0; bi<4; ++bi) acc[ai][bi] = (f4v){0,0,0,0};
      long hrow[4], arow[4];
      #pragma unroll
      for (int bi=0; bi<4; ++bi){
        const int n0 = N0 + bi*16;
        const int j  = n0 >> 5;
        const int bb = (n0 & 31) + c16;
        const int t  = d ? (LSEQ-1 - (ci*Tc + j)) : (ci*Tc + j);
        hrow[bi] = ((long)t*NB + bb)*H2;
      }
      #pragma unroll
      for (int ai=0; ai<4; ++ai) arow[ai] = ((long)d*G4 + M0 + ai*16 + c16)*H2;

      for (int kk = 0; kk < 50; ++kk){
        const int ko = kk*32 + q*8;
        h8v Ah[4], Bh[4];
        #pragma unroll
        for (int ai=0; ai<4; ++ai) Ah[ai] = ldv(p.w1ih + arow[ai] + ko);
        #pragma unroll
        for (int bi=0; bi<4; ++bi) Bh[bi] = ldv(p.h0 + hrow[bi] + ko);
        #pragma unroll
        for (int ai=0; ai<4; ++ai)
          #pragma unroll
          for (int bi=0; bi<4; ++bi)
            acc[ai][bi] = __builtin_amdgcn_mfma_f32_16x16x32_f16(Ah[ai], Bh[bi], acc[ai][bi], 0, 0, 0);
      }
      #pragma unroll
      for (int ai=0; ai<4; ++ai){
        const int row0 = M0 + ai*16 + q*4;
        const f4v bv = *(const f4v*)(p.bias1 + d*G4 + row0);
        #pragma unroll
        for (int bi=0; bi<4; ++bi){
          const int n0 = N0 + bi*16;
          const int j  = n0 >> 5;
          const int bb = (n0 & 31) + c16;
          f4v val = acc[ai][bi] + bv;
          *(f4v*)(p.gx1 + ((((long)d*Tc + j)*800 + (row0 >> 2))*NB + bb)*4) = val;
        }
      }
    }
    gbar(p.barG, ++ep);
    // ---------- recurrent steps (fence-light abar, active WGs) ----------
    if (act){
      f4v accNext = *(const f4v*)(p.gx1 + ((((long)dir*Tc + 0)*800 + (rowb >> 2))*NB + b)*4);
      for (int sl = 0; sl < Tc; ++sl){
        const int s  = ci*Tc + sl;
        f4v acc = accNext;
        f4v accl = {0.f,0.f,0.f,0.f};
        if (s > 0){
          const long hb = ((long)((s-1)&1)*NB + b)*H2 + dir*HID;
          const _Float16* rh = p.r1h + hb;
          const _Float16* rl = p.r1l + hb;
          const _Float16* wl = wlds + lw*WP;
          #pragma unroll
          for (int kk = 0; kk < 25; ++kk){
            const int ko = kk*32 + q*8;
            const h8v aw = *(const h8v*)(wl + ko);
            acc  = __builtin_amdgcn_mfma_f32_16x16x32_f16(aw, ldv(rh + ko), acc,  0, 0, 0);
            accl = __builtin_amdgcn_mfma_f32_16x16x32_f16(aw, ldv(rl + ko), accl, 0, 0, 0);
          }
        }
        const float si = 1.f/(1.f + __expf(-(acc[0] + accl[0]*ISC)));
        const float sf = 1.f/(1.f + __expf(-(acc[1] + accl[1]*ISC)));
        const float so = 1.f/(1.f + __expf(-(acc[3] + accl[3]*ISC)));
        cst = sf*cst + si*tanhf(acc[2] + accl[2]*ISC);
        const float h = so*tanhf(cst);
        const _Float16 hi = (_Float16)h;
        hT[0][ulocal][b] = hi;
        hT[1][ulocal][b] = (_Float16)((h - (float)hi)*SCAL);
        __syncthreads();
        {
          const int tid = threadIdx.x;
          if (tid < 64){
            const int part = tid >> 5, bb = tid & 31;
            const int slot = s % SL;
            h8v v;
            #pragma unroll
            for (int uu = 0; uu < 8; ++uu) v[uu] = hT[part][uu][bb];
            *(h8v*)((part ? p.h1wl : p.h1wh) + ((long)slot*NB + bb)*H2 + dir*HID + wgd*8) = v;
            union { h8v v; u64 u[2]; } pv; pv.v = v;
            u64* d = (u64*)((part ? p.r1l : p.r1h)
                    + ((long)(s&1)*NB + bb)*H2 + dir*HID + wgd*8);
            ring_pub(d, pv.u[0], pv.u[1]);
          }
        }
        // prefetch next gx1 (immutable within chunk) before the barrier
        if (sl + 1 < Tc)
          accNext = *(const f4v*)(p.gx1 + ((((long)dir*Tc + sl+1)*800 + (rowb >> 2))*NB + b)*4);
        abar(barS, s+1, wgd, 100);
      }
    }
    gbar(p.barG, ++ep);
    // ---------- logits phase ----------
    for (int pi = blockIdx.x; pi < 2*Tc; pi += gridDim.x){
      const int sl = pi >> 1, d = pi & 1;
      const int s  = ci*Tc + sl;
      const int t  = d ? (LSEQ-1-s) : s;
      const int slot = s % SL;
      const int bb = threadIdx.x & 31;
      const int k0 = threadIdx.x >> 5;
      const _Float16* hp  = p.h1wh + ((long)slot*NB + bb)*H2 + d*HID;
      const _Float16* hp2 = p.h1wl + ((long)slot*NB + bb)*H2 + d*HID;
      float* lp = (d ? p.logits1 : p.logits0) + ((long)t*NB + bb)*20;
      for (int k = k0; k < 20; k += 8){
        const float* wrow = p.w_lin + (long)k*H2 + d*HID;
        float acc2 = 0.f;
        for (int u = 0; u < HID; u += 8){
          h8v hv = ldv(hp + u);
          h8v lv = ldv(hp2 + u);
          #pragma unroll
          for (int j2 = 0; j2 < 8; ++j2)
            acc2 += ((float)hv[j2] + (float)lv[j2]*ISC) * wrow[u + j2];
        }
        lp[k] = acc2;
      }
    }
    gbar(p.barG, ++ep);
  }
}

// ---- head: logits -> softmax over BATCH axis -> angles -> dvec (reshape-scramble aware)
__global__ void head_kernel(P p){
  const int l = blockIdx.x;
  const int tid = threadIdx.x;
  __shared__ float lg[NB][20];
  __shared__ float sA[20][3], cA2[20][3];
  if (tid < 60){
    const float a = p.alphabet[tid];
    sA[tid/3][tid%3]  = sinf(a);
    cA2[tid/3][tid%3] = cosf(a);
  }
  for (int i = tid; i < NB*20; i += blockDim.x){
    const int bb = i / 20, k = i % 20;
    lg[bb][k] = p.logits0[((long)l*NB + bb)*20 + k] +
                p.logits1[((long)l*NB + bb)*20 + k] + p.b_lin[k];
  }
  __syncthreads();
  if (tid < 20){
    float mx = -1e30f;
    for (int bb=0; bb<NB; ++bb) mx = fmaxf(mx, lg[bb][tid]);
    float sum = 0.f;
    for (int bb=0; bb<NB; ++bb) sum += expf(lg[bb][tid] - mx);
    const float inv = 1.f/sum;
    for (int bb=0; bb<NB; ++bb) lg[bb][tid] = expf(lg[bb][tid] - mx)*inv;
  }
  __syncthreads();
  if (tid < 96){
    const int bb = tid/3, dd = tid%3;     // angle source (ang[l][bb][dd])
    const int pp = tid >> 5;              // scan row within step-triple
    const int j  = tid & 31;              // NeRF lane (column of phis)
    float ss = 0.f, cc = 0.f;
    #pragma unroll
    for (int k=0; k<20; ++k){ ss += lg[bb][k]*sA[k][dd]; cc += lg[bb][k]*cA2[k][dd]; }
    const float phi = atan2f(ss, cc);
    const float BL[3] = {145.801f, 152.326f, 132.868f};
    const float BA[3] = {2.124f, 1.941f, 2.028f};
    const float r = BL[pp], th = BA[pp];
    float* dv = p.dvec + ((long)(l*3 + pp)*NB + j)*4;
    dv[0] = -r*cosf(th);
    dv[1] = r*sinf(th)*cosf(phi);
    dv[2] = r*sinf(th)*sinf(phi);
  }
}

// ---- NeRF extension: strictly sequential, 1 lane per scan column.
__global__ void nerf_kernel(P p){
  const int bb = threadIdx.x;
  if (bb >= NB) return;
  float ax=0.f,ay=0.f,az=0.f, bx=100.f,by=0.f,bz=0.f, cx=200.f,cy=100.f,cz=0.f;
  for (int i = 0; i < 3*LSEQ; ++i){
    const float* dv = p.dvec + ((long)i*NB + bb)*4;
    const float d0=dv[0], d1=dv[1], d2=dv[2];
    float ux=cx-bx, uy=cy-by, uz=cz-bz;
    float inv = 1.f/(sqrtf(ux*ux+uy*uy+uz*uz)+1e-12f);
    ux*=inv; uy*=inv; uz*=inv;
    const float px=bx-ax, py=by-ay, pz=bz-az;
    float nx=py*uz-pz*uy, ny=pz*ux-px*uz, nz=px*uy-py*ux;
    inv = 1.f/(sqrtf(nx*nx+ny*ny+nz*nz)+1e-12f);
    nx*=inv; ny*=inv; nz*=inv;
    const float mx=ny*uz-nz*uy, my=nz*ux-nx*uz, mz=nx*uy-ny*ux;
    const float Dx = cx + d0*ux + d1*mx + d2*nx;
    const float Dy = cy + d0*uy + d1*my + d2*ny;
    const float Dz = cz + d0*uz + d1*mz + d2*nz;
    float* o = p.out + ((long)i*NB + bb)*3;
    o[0]=Dx; o[1]=Dy; o[2]=Dz;
    ax=bx; ay=by; az=bz;
    bx=cx; by=cy; bz=cz;
    cx=Dx; cy=Dy; cz=Dz;
  }
}

extern "C" void kernel_launch(void* const* d_in, const int* in_sizes, int n_in,
                              void* d_out, int out_size, void* d_ws, size_t ws_size,
                              hipStream_t stream){
  P p{};
  p.x      = (const float*)d_in[0];
  p.w_ih0  = (const float*)d_in[1];
  p.w_hh0  = (const float*)d_in[2];
  p.b_ih0  = (const float*)d_in[3];
  p.b_hh0  = (const float*)d_in[4];
  p.w_ih1  = (const float*)d_in[5];
  p.w_hh1  = (const float*)d_in[6];
  p.b_ih1  = (const float*)d_in[7];
  p.b_hh1  = (const float*)d_in[8];
  p.w_lin  = (const float*)d_in[9];
  p.b_lin  = (const float*)d_in[10];
  p.alphabet = (const float*)d_in[11];
  p.out    = (float*)d_out;

  char* base = (char*)d_ws;
  size_t off = 0;
  auto alloc = [&](size_t bytes)->void*{
    void* r = base + off;
    off = (off + bytes + 255) & ~(size_t)255;
    return r;
  };
  p.h0      = (_Float16*)alloc((size_t)LSEQ*NB*H2*2);        // 71.68 MB
  p.hr0h    = (_Float16*)alloc((size_t)2*NB*H2*2);           // 0.2 MB (single copy)
  p.hr0l    = (_Float16*)alloc((size_t)2*NB*H2*2);
  p.r1h     = (_Float16*)alloc((size_t)2*NB*H2*2);
  p.r1l     = (_Float16*)alloc((size_t)2*NB*H2*2);
  p.w0hh    = (_Float16*)alloc((size_t)2*G4*HID*2);          // 10.24 MB
  p.w1hh    = (_Float16*)alloc((size_t)2*G4*HID*2);          // 10.24 MB
  p.w1ih    = (_Float16*)alloc((size_t)2*G4*H2*2);           // 20.48 MB
  p.w0ih    = (_Float16*)alloc((size_t)2*G4*DKP*2);
  p.xp      = (_Float16*)alloc((size_t)LSEQ*NB*DKP*2);
  p.bias0   = (float*)alloc((size_t)2*G4*4);
  p.bias1   = (float*)alloc((size_t)2*G4*4);
  p.logits0 = (float*)alloc((size_t)LSEQ*NB*20*4);
  p.logits1 = (float*)alloc((size_t)LSEQ*NB*20*4);
  p.dvec    = (float*)alloc((size_t)3*LSEQ*NB*4*4);
  p.bar0    = (int*)alloc((size_t)2*RST*4);
  p.barG    = (int*)alloc((size_t)BARN*4);
  p.barS    = (int*)alloc((size_t)2*RST*4);

  const int cands[5] = {140, 100, 28, 20, 4};   // must divide 700 and be %4==0
  int Tc = 4;
  for (int i = 0; i < 5; ++i){
    const size_t need = off
      + (size_t)2*cands[i]*800*NB*4*4 + 256
      + (size_t)2*(cands[i]+1)*NB*H2*2 + 512;
    if (need <= ws_size){ Tc = cands[i]; break; }
  }
  p.gx1  = (float*)alloc((size_t)2*Tc*800*NB*4*4);
  p.h1wh = (_Float16*)alloc((size_t)(Tc+1)*NB*H2*2);
  p.h1wl = (_Float16*)alloc((size_t)(Tc+1)*NB*H2*2);
  p.Tc = Tc;
  p.nchunks = LSEQ / Tc;

  hipLaunchKernelGGL(prep_w, dim3(1024), dim3(256), 0, stream, p.w_hh0, p.w0hh, HID, HID);
  hipLaunchKernelGGL(prep_w, dim3(1024), dim3(256), 0, stream, p.w_hh1, p.w1hh, HID, HID);
  hipLaunchKernelGGL(prep_w, dim3(2048), dim3(256), 0, stream, p.w_ih1, p.w1ih, H2, H2);
  hipLaunchKernelGGL(prep_w, dim3(256),  dim3(256), 0, stream, p.w_ih0, p.w0ih, DIN, DKP);
  hipLaunchKernelGGL(prep_xpad, dim3(512), dim3(256), 0, stream, p.x, p.xp);
  hipLaunchKernelGGL(prep_bias, dim3(32), dim3(256), 0, stream,
                     p.b_ih0, p.b_hh0, p.b_ih1, p.b_hh1, p.bias0, p.bias1,
                     p.bar0, p.barG, p.barS);

  void* args[] = { &p };
  hipLaunchCooperativeKernel((void*)layer0_kernel, dim3(100), dim3(512), args, 0, stream);
  hipLaunchCooperativeKernel((void*)layer1_kernel, dim3(256), dim3(256), args, 0, stream);
  hipLaunchKernelGGL(head_kernel, dim3(LSEQ), dim3(256), 0, stream, p);
  hipLaunchKernelGGL(nerf_kernel, dim3(1), dim3(64), 0, stream, p);
}

// Round 12
// 18978.116 us; speedup vs baseline: 1.8628x; 1.0397x over previous
//
#include <hip/hip_runtime.h>

#define LSEQ 700
#define NB   32
#define DIN  41
#define HID  800
#define G4   3200   // 4*H gate rows
#define H2   1600   // 2*H
#define DKP  64     // Din padded to MFMA K granularity
#define RDEPTH 8    // ring depth 8 — slots recycle every 8 steps, so ONE
                    // acquire-inv per 8 steps provably suffices (write-once-per-period)
#define WP   808    // LDS weight row stride (f16): 1616B -> 2-way bank alias (free)

#define SCAL 2048.f
#define ISC  (1.f/2048.f)

// full-grid gbar region: 256 arrive flags (64B stride) + 64 go words (64B stride)
#define GOOFF (256*16)
#define BARN  (256*16 + 64*16)
// per-direction step-barrier region: 64B-strided flags
#define RST   (192*16)

typedef _Float16 h8v __attribute__((ext_vector_type(8)));  // 8 f16 = 4 VGPRs (MFMA A/B frag)
typedef float    f4v __attribute__((ext_vector_type(4)));
typedef unsigned long long u64;

struct P {
  const float *x, *w_ih0, *w_hh0, *b_ih0, *b_hh0;
  const float *w_ih1, *w_hh1, *b_ih1, *b_hh1;
  const float *w_lin, *b_lin, *alphabet;
  _Float16 *h0;                    // [t][b][dir*800+u] f16 hi — full history (layer1 GEMM input)
  _Float16 *hr0h, *hr0l;           // layer0 depth-8 ring [slot][b][dir*800+u]
  _Float16 *r1h,  *r1l;            // layer1 depth-8 ring
  _Float16 *h1wh, *h1wl;           // layer1 SL ring [slot][b][dir*800+u] (logits reads after gbar)
  _Float16 *w0hh, *w1hh;           // [dir][permrow 4u+g][800]
  _Float16 *w1ih;                  // [dir][permrow][1600]
  _Float16 *w0ih;                  // [dir][permrow][64]
  _Float16 *xp;                    // [t][b][64]
  float *bias0, *bias1;            // [dir][permrow]
  float *logits0, *logits1;        // [t][b][20]
  float *dvec;                     // [3L][j][4]
  float *gx1;                      // [d][sl][unit][b][4] f32
  float *out;
  int *bar0;                       // layer0 per-dir step flags [2][RST]
  int *barG;                       // layer1 full-grid gbar (phase boundaries)
  int *barS;                       // layer1 per-dir step flags [2][RST]
  int Tc, nchunks;
};

__device__ __forceinline__ h8v ldv(const _Float16* p_){ return *(const h8v*)p_; }

// Coherent flag poll: agent-scope RMW executes AT the LLC (proven R7).
__device__ __forceinline__ int poll(int* f){
  return __hip_atomic_fetch_add(f, 0, __ATOMIC_RELAXED, __HIP_MEMORY_SCOPE_AGENT);
}

// Ring publish: agent-scope atomic_exchange; returned old value kept live so
// vmcnt-ack == data committed at the LLC coherence point (proven R8).
__device__ __forceinline__ void ring_pub(u64* d, u64 v0, u64 v1){
  u64 o0 = __hip_atomic_exchange(d,   v0, __ATOMIC_RELAXED, __HIP_MEMORY_SCOPE_AGENT);
  u64 o1 = __hip_atomic_exchange(d+1, v1, __ATOMIC_RELAXED, __HIP_MEMORY_SCOPE_AGENT);
  asm volatile("" :: "v"(o0), "v"(o1));   // keep returns live: ack == LLC commit
}

// Full-grid fenced barrier — layer1 phase boundaries (bulk cached-store
// handoffs: needs both wbl2 release and inv acquire). R7-verbatim.
__device__ __forceinline__ void gbar(int* bar, int ep){
  __syncthreads();
  if (threadIdx.x == 0){
    __builtin_amdgcn_fence(__ATOMIC_RELEASE, "agent");   // L2 writeback to coherence point
    __hip_atomic_store(&bar[blockIdx.x*16], ep, __ATOMIC_RELAXED, __HIP_MEMORY_SCOPE_AGENT);
  }
  if (blockIdx.x == 0){
    for (int i = threadIdx.x; i < (int)gridDim.x; i += blockDim.x)
      while (poll(&bar[i*16]) < ep)
        __builtin_amdgcn_s_sleep(1);
    __syncthreads();
    if (threadIdx.x < 64)
      __hip_atomic_store(&bar[GOOFF + threadIdx.x*16], ep, __ATOMIC_RELAXED, __HIP_MEMORY_SCOPE_AGENT);
  } else {
    if (threadIdx.x == 0){
      while (poll(&bar[GOOFF + (blockIdx.x & 63)*16]) < ep)
        __builtin_amdgcn_s_sleep(1);
    }
  }
  __syncthreads();
  if (threadIdx.x < 64)
    __builtin_amdgcn_fence(__ATOMIC_ACQUIRE, "agent");   // single buffer_inv per WG
  __syncthreads();
}

// Per-direction step barrier: no release fence (exchange-publish already
// LLC-committed; entry __syncthreads drains every wave's acks before the flag
// store); RMW poll. Acquire-inv only ONCE PER RDEPTH steps: ring slots recycle
// every RDEPTH steps, so between any two writes to the same address every
// consumer executes exactly one invalidate — each generation's single read is
// either a fresh LLC pull (post-inv) or a correctly-cached value (pre-rewrite).
__device__ __forceinline__ void abar(int* bar, int ep, int wgd, int n){
  __syncthreads();                       // all waves' exchanges acked -> data at LLC
  if (threadIdx.x == 0)
    __hip_atomic_store(&bar[wgd*16], ep, __ATOMIC_RELAXED, __HIP_MEMORY_SCOPE_AGENT);
  if (threadIdx.x < n){
    while (poll(&bar[threadIdx.x*16]) < ep)
      __builtin_amdgcn_s_sleep(1);
  }
  __syncthreads();
  if ((ep & (RDEPTH-1)) == 0){
    if (threadIdx.x < 64)
      __builtin_amdgcn_fence(__ATOMIC_ACQUIRE, "agent"); // amortized: 1 inv / 8 steps
    __syncthreads();
  }
}

// ---- prep: permuted-row f16 weights. newrow = 4*u + gate (gate order i,f,g,o)
__global__ void prep_w(const float* __restrict__ src, _Float16* __restrict__ dst,
                       int Ks, int Kd){
  const long n = (long)2*G4*Kd;
  for (long i = blockIdx.x*(long)blockDim.x + threadIdx.x; i < n; i += (long)gridDim.x*blockDim.x){
    const int k  = (int)(i % Kd);
    const long rr = i / Kd;
    const int nr = (int)(rr % G4);
    const int d  = (int)(rr / G4);
    float v = 0.f;
    if (k < Ks){
      const int u = nr >> 2, g = nr & 3;
      v = src[((long)d*G4 + g*HID + u)*Ks + k];
    }
    dst[i] = (_Float16)v;
  }
}

__global__ void prep_xpad(const float* __restrict__ x, _Float16* __restrict__ dst){
  const long n = (long)LSEQ*NB*DKP;
  for (long i = blockIdx.x*(long)blockDim.x + threadIdx.x; i < n; i += (long)gridDim.x*blockDim.x){
    const int k = (int)(i % DKP);
    const long rr = i / DKP;
    const int bb = (int)(rr % NB);
    const int t  = (int)(rr / NB);
    float v = 0.f;
    if (k < DIN) v = x[((long)bb*LSEQ + t)*DIN + k];   // x is [B][L][Din]
    dst[i] = (_Float16)v;
  }
}

__global__ void prep_bias(const float* bi0, const float* bh0, const float* bi1, const float* bh1,
                          float* o0, float* o1, int* bar0, int* barG, int* barS){
  const int tid = blockIdx.x*blockDim.x + threadIdx.x;
  for (int i = tid; i < 2*G4; i += gridDim.x*blockDim.x){
    const int nr = i % G4, d = i / G4;
    const int u = nr >> 2, g = nr & 3;
    const int old = d*G4 + g*HID + u;
    o0[i] = bi0[old] + bh0[old];
    o1[i] = bi1[old] + bh1[old];
  }
  for (int i = tid; i < 2*RST; i += gridDim.x*blockDim.x){ bar0[i] = 0; barS[i] = 0; }
  for (int i = tid; i < BARN;  i += gridDim.x*blockDim.x)  barG[i] = 0;
}

// ---- layer 0: grid 100, 512 threads (8 waves), 50 WGs/dir. R9-verbatim compute;
// depth-8 ring + amortized inv.
__global__ void __launch_bounds__(512, 1) layer0_kernel(P p){
  const int wg  = blockIdx.x;          // 0..99
  const int dir = wg / 50;
  const int wgd = wg % 50;
  const int wid = threadIdx.x >> 6;    // 0..7
  const int lane = threadIdx.x & 63;
  const int q = lane >> 4, c16 = lane & 15;
  const int wv = wgd*8 + wid;          // 0..399
  const int m  = wv >> 1;              // Mtile 0..199
  const int nt = wv & 1;
  const int b  = nt*16 + c16;
  const int ulocal = (wid >> 1)*4 + q; // 0..15: WG owns units 16*wgd..+16
  const int lw = (wid >> 1)*16 + c16;  // local weight row 0..63
  const int rowb = m*16 + q*4;
  float cst = 0.f;
  __shared__ _Float16 hT[2][16][32];
  __shared__ _Float16 wlds[64*WP];     // 103.4 KB: this WG's 64 W_hh gate rows

  // stage W_hh rows [dir*G4 + wgd*64 .. +64) into LDS once
  {
    const long base_row = (long)dir*G4 + wgd*64;
    for (int idx = threadIdx.x; idx < 6400; idx += 512){
      const int lr = idx / 100, c = idx % 100;
      *(h8v*)(wlds + lr*WP + c*8) = ldv(p.w0hh + (base_row + lr)*HID + c*8);
    }
  }
  __syncthreads();

  const long wih_row = ((long)dir*G4 + m*16 + c16)*DKP;
  int* bar = p.bar0 + dir*RST;
  const f4v bias = *(const f4v*)(p.bias0 + dir*G4 + rowb);

  // prologue: x-GEMM for s=0
  f4v xacc = {0.f,0.f,0.f,0.f};
  {
    const int t0 = dir ? (LSEQ-1) : 0;
    const long xb = ((long)t0*NB + b)*DKP;
    #pragma unroll
    for (int kk = 0; kk < 2; ++kk){
      const int ko = kk*32 + q*8;
      xacc = __builtin_amdgcn_mfma_f32_16x16x32_f16(
               ldv(p.w0ih + wih_row + ko), ldv(p.xp + xb + ko), xacc, 0, 0, 0);
    }
  }

  for (int s = 0; s < LSEQ; ++s){
    const int t  = dir ? (LSEQ-1-s) : s;
    f4v acc = xacc;
    f4v accl = {0.f,0.f,0.f,0.f};
    if (s > 0){
      const long hb = ((long)((s-1)&(RDEPTH-1))*NB + b)*H2 + dir*HID;
      const _Float16* rh = p.hr0h + hb;
      const _Float16* rl = p.hr0l + hb;
      const _Float16* wl = wlds + lw*WP;
      #pragma unroll
      for (int kk = 0; kk < 25; ++kk){
        const int ko = kk*32 + q*8;
        const h8v aw = *(const h8v*)(wl + ko);
        acc  = __builtin_amdgcn_mfma_f32_16x16x32_f16(aw, ldv(rh + ko), acc,  0, 0, 0);
        accl = __builtin_amdgcn_mfma_f32_16x16x32_f16(aw, ldv(rl + ko), accl, 0, 0, 0);
      }
    }
    const float gi = acc[0] + accl[0]*ISC + bias[0];
    const float gf = acc[1] + accl[1]*ISC + bias[1];
    const float gg = acc[2] + accl[2]*ISC + bias[2];
    const float go = acc[3] + accl[3]*ISC + bias[3];
    const float si = 1.f/(1.f + __expf(-gi));
    const float sf = 1.f/(1.f + __expf(-gf));
    const float so = 1.f/(1.f + __expf(-go));
    cst = sf*cst + si*tanhf(gg);
    const float h = so*tanhf(cst);
    const _Float16 hi = (_Float16)h;
    hT[0][ulocal][b] = hi;
    hT[1][ulocal][b] = (_Float16)((h - (float)hi)*SCAL);
    __syncthreads();
    {
      // publish: 128 threads each exchange one 16B share into the depth-8 ring
      // (LLC-committed by ack); h0 stays plain-cached (kernel-end flush).
      const int tid = threadIdx.x;
      if (tid < 128){
        const int part = tid >> 6;     // hi/lo
        const int ub = (tid >> 5) & 1; // unit block (8 units)
        const int bb = tid & 31;       // batch
        h8v v;
        #pragma unroll
        for (int uu = 0; uu < 8; ++uu) v[uu] = hT[part][ub*8 + uu][bb];
        if (part == 0)
          *(h8v*)(p.h0 + (long)t*NB*H2 + (long)bb*H2 + dir*HID + wgd*16 + ub*8) = v;
        union { h8v v; u64 u[2]; } pv; pv.v = v;
        u64* d = (u64*)((part ? p.hr0l : p.hr0h)
                + ((long)(s&(RDEPTH-1))*NB + bb)*H2 + dir*HID + wgd*16 + ub*8);
        ring_pub(d, pv.u[0], pv.u[1]);
      }
    }
    // prefetch next step's x-GEMM before the barrier
    f4v xn = {0.f,0.f,0.f,0.f};
    if (s + 1 < LSEQ){
      const int t2 = dir ? (LSEQ-2-s) : (s+1);
      const long xb2 = ((long)t2*NB + b)*DKP;
      #pragma unroll
      for (int kk = 0; kk < 2; ++kk){
        const int ko = kk*32 + q*8;
        xn = __builtin_amdgcn_mfma_f32_16x16x32_f16(
               ldv(p.w0ih + wih_row + ko), ldv(p.xp + xb2 + ko), xn, 0, 0, 0);
      }
    }
    xacc = xn;
    abar(bar, s+1, wgd, 50);
  }
}

// ---- layer 1: grid 256, 4 waves. R9-verbatim; depth-8 ring + amortized inv.
__global__ void __launch_bounds__(256, 1) layer1_kernel(P p){
  const int wg  = blockIdx.x;
  const int dir = wg >> 7;
  const int wgd = wg & 127;
  const int wid = threadIdx.x >> 6;
  const int lane = threadIdx.x & 63;
  const int q = lane >> 4, c16 = lane & 15;
  const bool act = (wgd < 100);
  const int wv = wgd*4 + wid;
  const int m  = wv >> 1;
  const int nt = wv & 1;
  const int b  = nt*16 + c16;
  const int ulocal = (wid >> 1)*4 + q;
  const int lw = (wid >> 1)*16 + c16;
  const int rowb = m*16 + q*4;
  float cst = 0.f;
  __shared__ _Float16 hT[2][8][32];
  __shared__ _Float16 wlds[32*WP];
  int* barS = p.barS + dir*RST;
  const int Tc = p.Tc;
  const int SL = Tc + 1;
  const int ntN = Tc >> 2;
  const int tilesPerDir = 25*ntN;
  const int TILES = 2*tilesPerDir;
  int ep = 0;

  if (act){
    const long base_row = (long)dir*G4 + wgd*32;
    for (int idx = threadIdx.x; idx < 3200; idx += 256){
      const int lr = idx / 100, c = idx % 100;
      *(h8v*)(wlds + lr*WP + c*8) = ldv(p.w1hh + (base_row + lr)*HID + c*8);
    }
  }
  __syncthreads();

  for (int ci = 0; ci < p.nchunks; ++ci){
    // ---------- GEMM phase ----------
    for (int tile = blockIdx.x; tile < TILES; tile += gridDim.x){
      const int d   = tile / tilesPerDir;
      const int rem = tile % tilesPerDir;
      const int mi  = rem / ntN;
      const int ni  = rem % ntN;
      const int M0  = mi*128 + (wid >> 1)*64;
      const int N0  = ni*128 + (wid & 1)*64;
      f4v acc[4][4];
      #pragma unroll
      for (int ai=0; ai<4; ++ai)
        #pragma unroll
        for (int bi=0; bi<4; ++bi) acc[ai][bi] = (f4v){0,0,0,0};
      long hrow[4], arow[4];
      #pragma unroll
      for (int bi=0; bi<4; ++bi){
        const int n0 = N0 + bi*16;
        const int j  = n0 >> 5;
        const int bb = (n0 & 31) + c16;
        const int t  = d ? (LSEQ-1 - (ci*Tc + j)) : (ci*Tc + j);
        hrow[bi] = ((long)t*NB + bb)*H2;
      }
      #pragma unroll
      for (int ai=0; ai<4; ++ai) arow[ai] = ((long)d*G4 + M0 + ai*16 + c16)*H2;

      for (int kk = 0; kk < 50; ++kk){
        const int ko = kk*32 + q*8;
        h8v Ah[4], Bh[4];
        #pragma unroll
        for (int ai=0; ai<4; ++ai) Ah[ai] = ldv(p.w1ih + arow[ai] + ko);
        #pragma unroll
        for (int bi=0; bi<4; ++bi) Bh[bi] = ldv(p.h0 + hrow[bi] + ko);
        #pragma unroll
        for (int ai=0; ai<4; ++ai)
          #pragma unroll
          for (int bi=0; bi<4; ++bi)
            acc[ai][bi] = __builtin_amdgcn_mfma_f32_16x16x32_f16(Ah[ai], Bh[bi], acc[ai][bi], 0, 0, 0);
      }
      #pragma unroll
      for (int ai=0; ai<4; ++ai){
        const int row0 = M0 + ai*16 + q*4;
        const f4v bv = *(const f4v*)(p.bias1 + d*G4 + row0);
        #pragma unroll
        for (int bi=0; bi<4; ++bi){
          const int n0 = N0 + bi*16;
          const int j  = n0 >> 5;
          const int bb = (n0 & 31) + c16;
          f4v val = acc[ai][bi] + bv;
          *(f4v*)(p.gx1 + ((((long)d*Tc + j)*800 + (row0 >> 2))*NB + bb)*4) = val;
        }
      }
    }
    gbar(p.barG, ++ep);
    // ---------- recurrent steps (amortized-inv abar, active WGs) ----------
    if (act){
      f4v accNext = *(const f4v*)(p.gx1 + ((((long)dir*Tc + 0)*800 + (rowb >> 2))*NB + b)*4);
      for (int sl = 0; sl < Tc; ++sl){
        const int s  = ci*Tc + sl;
        f4v acc = accNext;
        f4v accl = {0.f,0.f,0.f,0.f};
        if (s > 0){
          const long hb = ((long)((s-1)&(RDEPTH-1))*NB + b)*H2 + dir*HID;
          const _Float16* rh = p.r1h + hb;
          const _Float16* rl = p.r1l + hb;
          const _Float16* wl = wlds + lw*WP;
          #pragma unroll
          for (int kk = 0; kk < 25; ++kk){
            const int ko = kk*32 + q*8;
            const h8v aw = *(const h8v*)(wl + ko);
            acc  = __builtin_amdgcn_mfma_f32_16x16x32_f16(aw, ldv(rh + ko), acc,  0, 0, 0);
            accl = __builtin_amdgcn_mfma_f32_16x16x32_f16(aw, ldv(rl + ko), accl, 0, 0, 0);
          }
        }
        const float si = 1.f/(1.f + __expf(-(acc[0] + accl[0]*ISC)));
        const float sf = 1.f/(1.f + __expf(-(acc[1] + accl[1]*ISC)));
        const float so = 1.f/(1.f + __expf(-(acc[3] + accl[3]*ISC)));
        cst = sf*cst + si*tanhf(acc[2] + accl[2]*ISC);
        const float h = so*tanhf(cst);
        const _Float16 hi = (_Float16)h;
        hT[0][ulocal][b] = hi;
        hT[1][ulocal][b] = (_Float16)((h - (float)hi)*SCAL);
        __syncthreads();
        {
          const int tid = threadIdx.x;
          if (tid < 64){
            const int part = tid >> 5, bb = tid & 31;
            const int slot = s % SL;
            h8v v;
            #pragma unroll
            for (int uu = 0; uu < 8; ++uu) v[uu] = hT[part][uu][bb];
            *(h8v*)((part ? p.h1wl : p.h1wh) + ((long)slot*NB + bb)*H2 + dir*HID + wgd*8) = v;
            union { h8v v; u64 u[2]; } pv; pv.v = v;
            u64* d = (u64*)((part ? p.r1l : p.r1h)
                    + ((long)(s&(RDEPTH-1))*NB + bb)*H2 + dir*HID + wgd*8);
            ring_pub(d, pv.u[0], pv.u[1]);
          }
        }
        // prefetch next gx1 (immutable within chunk) before the barrier
        if (sl + 1 < Tc)
          accNext = *(const f4v*)(p.gx1 + ((((long)dir*Tc + sl+1)*800 + (rowb >> 2))*NB + b)*4);
        abar(barS, s+1, wgd, 100);
      }
    }
    gbar(p.barG, ++ep);
    // ---------- logits phase ----------
    for (int pi = blockIdx.x; pi < 2*Tc; pi += gridDim.x){
      const int sl = pi >> 1, d = pi & 1;
      const int s  = ci*Tc + sl;
      const int t  = d ? (LSEQ-1-s) : s;
      const int slot = s % SL;
      const int bb = threadIdx.x & 31;
      const int k0 = threadIdx.x >> 5;
      const _Float16* hp  = p.h1wh + ((long)slot*NB + bb)*H2 + d*HID;
      const _Float16* hp2 = p.h1wl + ((long)slot*NB + bb)*H2 + d*HID;
      float* lp = (d ? p.logits1 : p.logits0) + ((long)t*NB + bb)*20;
      for (int k = k0; k < 20; k += 8){
        const float* wrow = p.w_lin + (long)k*H2 + d*HID;
        float acc2 = 0.f;
        for (int u = 0; u < HID; u += 8){
          h8v hv = ldv(hp + u);
          h8v lv = ldv(hp2 + u);
          #pragma unroll
          for (int j2 = 0; j2 < 8; ++j2)
            acc2 += ((float)hv[j2] + (float)lv[j2]*ISC) * wrow[u + j2];
        }
        lp[k] = acc2;
      }
    }
    gbar(p.barG, ++ep);
  }
}

// ---- head: logits -> softmax over BATCH axis -> angles -> dvec ----
__global__ void head_kernel(P p){
  const int l = blockIdx.x;
  const int tid = threadIdx.x;
  __shared__ float lg[NB][20];
  __shared__ float sA[20][3], cA2[20][3];
  if (tid < 60){
    const float a = p.alphabet[tid];
    sA[tid/3][tid%3]  = sinf(a);
    cA2[tid/3][tid%3] = cosf(a);
  }
  for (int i = tid; i < NB*20; i += blockDim.x){
    const int bb = i / 20, k = i % 20;
    lg[bb][k] = p.logits0[((long)l*NB + bb)*20 + k] +
                p.logits1[((long)l*NB + bb)*20 + k] + p.b_lin[k];
  }
  __syncthreads();
  if (tid < 20){
    float mx = -1e30f;
    for (int bb=0; bb<NB; ++bb) mx = fmaxf(mx, lg[bb][tid]);
    float sum = 0.f;
    for (int bb=0; bb<NB; ++bb) sum += expf(lg[bb][tid] - mx);
    const float inv = 1.f/sum;
    for (int bb=0; bb<NB; ++bb) lg[bb][tid] = expf(lg[bb][tid] - mx)*inv;
  }
  __syncthreads();
  if (tid < 96){
    const int bb = tid/3, dd = tid%3;
    const int pp = tid >> 5;
    const int j  = tid & 31;
    float ss = 0.f, cc = 0.f;
    #pragma unroll
    for (int k=0; k<20; ++k){ ss += lg[bb][k]*sA[k][dd]; cc += lg[bb][k]*cA2[k][dd]; }
    const float phi = atan2f(ss, cc);
    const float BL[3] = {145.801f, 152.326f, 132.868f};
    const float BA[3] = {2.124f, 1.941f, 2.028f};
    const float r = BL[pp], th = BA[pp];
    float* dv = p.dvec + ((long)(l*3 + pp)*NB + j)*4;
    dv[0] = -r*cosf(th);
    dv[1] = r*sinf(th)*cosf(phi);
    dv[2] = r*sinf(th)*sinf(phi);
  }
}

// ---- NeRF extension: strictly sequential, 1 lane per scan column.
__global__ void nerf_kernel(P p){
  const int bb = threadIdx.x;
  if (bb >= NB) return;
  float ax=0.f,ay=0.f,az=0.f, bx=100.f,by=0.f,bz=0.f, cx=200.f,cy=100.f,cz=0.f;
  for (int i = 0; i < 3*LSEQ; ++i){
    const float* dv = p.dvec + ((long)i*NB + bb)*4;
    const float d0=dv[0], d1=dv[1], d2=dv[2];
    float ux=cx-bx, uy=cy-by, uz=cz-bz;
    float inv = 1.f/(sqrtf(ux*ux+uy*uy+uz*uz)+1e-12f);
    ux*=inv; uy*=inv; uz*=inv;
    const float px=bx-ax, py=by-ay, pz=bz-az;
    float nx=py*uz-pz*uy, ny=pz*ux-px*uz, nz=px*uy-py*ux;
    inv = 1.f/(sqrtf(nx*nx+ny*ny+nz*nz)+1e-12f);
    nx*=inv; ny*=inv; nz*=inv;
    const float mx=ny*uz-nz*uy, my=nz*ux-nx*uz, mz=nx*uy-ny*ux;
    const float Dx = cx + d0*ux + d1*mx + d2*nx;
    const float Dy = cy + d0*uy + d1*my + d2*ny;
    const float Dz = cz + d0*uz + d1*mz + d2*nz;
    float* o = p.out + ((long)i*NB + bb)*3;
    o[0]=Dx; o[1]=Dy; o[2]=Dz;
    ax=bx; ay=by; az=bz;
    bx=cx; by=cy; bz=cz;
    cx=Dx; cy=Dy; cz=Dz;
  }
}

extern "C" void kernel_launch(void* const* d_in, const int* in_sizes, int n_in,
                              void* d_out, int out_size, void* d_ws, size_t ws_size,
                              hipStream_t stream){
  P p{};
  p.x      = (const float*)d_in[0];
  p.w_ih0  = (const float*)d_in[1];
  p.w_hh0  = (const float*)d_in[2];
  p.b_ih0  = (const float*)d_in[3];
  p.b_hh0  = (const float*)d_in[4];
  p.w_ih1  = (const float*)d_in[5];
  p.w_hh1  = (const float*)d_in[6];
  p.b_ih1  = (const float*)d_in[7];
  p.b_hh1  = (const float*)d_in[8];
  p.w_lin  = (const float*)d_in[9];
  p.b_lin  = (const float*)d_in[10];
  p.alphabet = (const float*)d_in[11];
  p.out    = (float*)d_out;

  char* base = (char*)d_ws;
  size_t off = 0;
  auto alloc = [&](size_t bytes)->void*{
    void* r = base + off;
    off = (off + bytes + 255) & ~(size_t)255;
    return r;
  };
  p.h0      = (_Float16*)alloc((size_t)LSEQ*NB*H2*2);        // 71.68 MB
  p.hr0h    = (_Float16*)alloc((size_t)RDEPTH*NB*H2*2);      // depth-8 rings (~0.8MB each)
  p.hr0l    = (_Float16*)alloc((size_t)RDEPTH*NB*H2*2);
  p.r1h     = (_Float16*)alloc((size_t)RDEPTH*NB*H2*2);
  p.r1l     = (_Float16*)alloc((size_t)RDEPTH*NB*H2*2);
  p.w0hh    = (_Float16*)alloc((size_t)2*G4*HID*2);          // 10.24 MB
  p.w1hh    = (_Float16*)alloc((size_t)2*G4*HID*2);          // 10.24 MB
  p.w1ih    = (_Float16*)alloc((size_t)2*G4*H2*2);           // 20.48 MB
  p.w0ih    = (_Float16*)alloc((size_t)2*G4*DKP*2);
  p.xp      = (_Float16*)alloc((size_t)LSEQ*NB*DKP*2);
  p.bias0   = (float*)alloc((size_t)2*G4*4);
  p.bias1   = (float*)alloc((size_t)2*G4*4);
  p.logits0 = (float*)alloc((size_t)LSEQ*NB*20*4);
  p.logits1 = (float*)alloc((size_t)LSEQ*NB*20*4);
  p.dvec    = (float*)alloc((size_t)3*LSEQ*NB*4*4);
  p.bar0    = (int*)alloc((size_t)2*RST*4);
  p.barG    = (int*)alloc((size_t)BARN*4);
  p.barS    = (int*)alloc((size_t)2*RST*4);

  const int cands[5] = {140, 100, 28, 20, 4};   // must divide 700 and be %4==0
  int Tc = 4;
  for (int i = 0; i < 5; ++i){
    const size_t need = off
      + (size_t)2*cands[i]*800*NB*4*4 + 256
      + (size_t)2*(cands[i]+1)*NB*H2*2 + 512;
    if (need <= ws_size){ Tc = cands[i]; break; }
  }
  p.gx1  = (float*)alloc((size_t)2*Tc*800*NB*4*4);
  p.h1wh = (_Float16*)alloc((size_t)(Tc+1)*NB*H2*2);
  p.h1wl = (_Float16*)alloc((size_t)(Tc+1)*NB*H2*2);
  p.Tc = Tc;
  p.nchunks = LSEQ / Tc;

  hipLaunchKernelGGL(prep_w, dim3(1024), dim3(256), 0, stream, p.w_hh0, p.w0hh, HID, HID);
  hipLaunchKernelGGL(prep_w, dim3(1024), dim3(256), 0, stream, p.w_hh1, p.w1hh, HID, HID);
  hipLaunchKernelGGL(prep_w, dim3(2048), dim3(256), 0, stream, p.w_ih1, p.w1ih, H2, H2);
  hipLaunchKernelGGL(prep_w, dim3(256),  dim3(256), 0, stream, p.w_ih0, p.w0ih, DIN, DKP);
  hipLaunchKernelGGL(prep_xpad, dim3(512), dim3(256), 0, stream, p.x, p.xp);
  hipLaunchKernelGGL(prep_bias, dim3(32), dim3(256), 0, stream,
                     p.b_ih0, p.b_hh0, p.b_ih1, p.b_hh1, p.bias0, p.bias1,
                     p.bar0, p.barG, p.barS);

  void* args[] = { &p };
  hipLaunchCooperativeKernel((void*)layer0_kernel, dim3(100), dim3(512), args, 0, stream);
  hipLaunchCooperativeKernel((void*)layer1_kernel, dim3(256), dim3(256), args, 0, stream);
  hipLaunchKernelGGL(head_kernel, dim3(LSEQ), dim3(256), 0, stream, p);
  hipLaunchKernelGGL(nerf_kernel, dim3(1), dim3(64), 0, stream, p);
}